// Round 6
// baseline (3612.665 us; speedup 1.0000x reference)
//
#include <hip/hip_runtime.h>
#include <stdint.h>
#include <stddef.h>

typedef uint32_t u32;
typedef float v2f __attribute__((ext_vector_type(2)));
typedef _Float16 f16;
typedef f16 half4 __attribute__((ext_vector_type(4)));
typedef f16 half8 __attribute__((ext_vector_type(8)));
typedef float floatx4 __attribute__((ext_vector_type(4)));

// ---------------- problem constants (fixed by reference file) ----------------
#define NB    256      // batch B
#define LFULL 412      // L
#define NCH   3        // C
#define CTX   336      // context_length
#define NSAMP 100      // n_samples
#define TM1   383      // T-1 (T = L - MAX_LAG = 384)
#define HID   64
#define NIN   15
#define RTOT  25600    // NB*NSAMP
#define NCTXS 8601600u // RTOT*CTX
#define NSTEP 47       // H-1

#define DROWS   128    // rows per persistent decode block (16 per wave, 8 waves)
#define RPW     16     // rows per wave
#define DBLOCKS (RTOT / DROWS)  // 200 -> 1 dispatch round on 256 CUs

#define HSTR    72     // h-array LDS stride in halves (144 B, 16B-aligned, bank-spread)

#define JAX_PARTITIONABLE 1

__device__ const int c_LAGS[10] = {1,2,3,4,5,6,7,14,21,28};

__device__ inline v2f bc2(float x) { v2f r; r[0] = x; r[1] = x; return r; }

// ---------------- threefry2x32 (matches jax._src.prng) ----------------
__host__ __device__ inline void tf2x32(u32 k0, u32 k1, u32 x0, u32 x1, u32& o0, u32& o1) {
  const u32 ks2 = k0 ^ k1 ^ 0x1BD11BDAu;
#define TFR(r) { x0 += x1; x1 = (x1 << (r)) | (x1 >> (32 - (r))); x1 ^= x0; }
  x0 += k0; x1 += k1;
  TFR(13) TFR(15) TFR(26) TFR(6)
  x0 += k1; x1 += ks2 + 1u;
  TFR(17) TFR(29) TFR(16) TFR(24)
  x0 += ks2; x1 += k0 + 2u;
  TFR(13) TFR(15) TFR(26) TFR(6)
  x0 += k0; x1 += k1 + 3u;
  TFR(17) TFR(29) TFR(16) TFR(24)
  x0 += k1; x1 += ks2 + 4u;
  TFR(13) TFR(15) TFR(26) TFR(6)
  x0 += ks2; x1 += k0 + 5u;
#undef TFR
  o0 = x0; o1 = x1;
}

__host__ __device__ inline u32 split_word_legacy(u32 k0, u32 k1, u32 n, u32 j) {
  u32 o0, o1;
  if (j < n) { tf2x32(k0, k1, j, n + j, o0, o1); return o0; }
  tf2x32(k0, k1, j - n, j, o0, o1); return o1;
}

__host__ __device__ inline void jx_subkey(u32 k0, u32 k1, u32 n, u32 i, u32& s0, u32& s1) {
#if JAX_PARTITIONABLE
  (void)n; tf2x32(k0, k1, 0u, i, s0, s1);
#else
  s0 = split_word_legacy(k0, k1, n, 2u * i);
  s1 = split_word_legacy(k0, k1, n, 2u * i + 1u);
#endif
}

__device__ inline u32 jx_bits(u32 k0, u32 k1, u32 n, u32 i) {
#if JAX_PARTITIONABLE
  (void)n; u32 o0, o1; tf2x32(k0, k1, 0u, i, o0, o1); return o0 ^ o1;
#else
  u32 o0, o1;
  if (n == 1u) { tf2x32(k0, k1, 0u, 0u, o0, o1); return o0; }
  const u32 h = n >> 1;
  if (i < h) { tf2x32(k0, k1, i, h + i, o0, o1); return o0; }
  tf2x32(k0, k1, i - h, i, o0, o1); return o1;
#endif
}

// ---------------- JAX-exact float transforms ----------------
__device__ inline float jax_erfinv(float x) {
#pragma clang fp contract(off)
  float w = -log1pf(-x * x);
  float p;
  if (w < 5.0f) {
    w = w - 2.5f;
    p = 2.81022636e-08f;
    p = 3.43273939e-07f + p * w;
    p = -3.5233877e-06f + p * w;
    p = -4.39150654e-06f + p * w;
    p = 0.00021858087f + p * w;
    p = -0.00125372503f + p * w;
    p = -0.00417768164f + p * w;
    p = 0.246640727f + p * w;
    p = 1.50140941f + p * w;
  } else {
    w = sqrtf(w) - 3.0f;
    p = -0.000200214257f;
    p = 0.000100950558f + p * w;
    p = 0.00134934322f + p * w;
    p = -0.00367342844f + p * w;
    p = 0.00573950773f + p * w;
    p = -0.0076224613f + p * w;
    p = 0.00943887047f + p * w;
    p = 1.00167406f + p * w;
    p = 2.83297682f + p * w;
  }
  return p * x;
}

__device__ inline float u01_from_bits(u32 bits) {
  return __uint_as_float((bits >> 9) | 0x3f800000u) - 1.0f;
}

__device__ inline float normal_from_bits(u32 bits) {
#pragma clang fp contract(off)
  const float lo = -0.99999994f;
  const float u = u01_from_bits(bits);
  float r = u * 2.0f + lo;
  r = fmaxf(lo, r);
  return 1.41421356f * jax_erfinv(r);
}

__device__ float jax_gamma_one(u32 k0, u32 k1, float alpha) {
#pragma clang fp contract(off)
  const bool boost_mask = (alpha >= 1.0f);
  const float alpha_orig = alpha;
  const float a = boost_mask ? alpha : (alpha + 1.0f);
  const float d = a - 0.33333334f;
  const float c = 0.33333334f / sqrtf(d);
  u32 K0, K1, S0, S1;
  jx_subkey(k0, k1, 2u, 0u, K0, K1);
  jx_subkey(k0, k1, 2u, 1u, S0, S1);
  float u_boost = 1.0f;
  if (!boost_mask) u_boost = u01_from_bits(jx_bits(S0, S1, 1u, 0u));
  float X = 0.0f, V = 1.0f, U = 2.0f;
  while (true) {
    if (!(U >= 1.0f - 0.0331f * (X * X))) break;
    if (!(logf(U) >= 0.5f * X + d * ((1.0f - V) + logf(V)))) break;
    u32 nk0, nk1, xk0, xk1, uk0, uk1;
    jx_subkey(K0, K1, 3u, 0u, nk0, nk1);
    jx_subkey(K0, K1, 3u, 1u, xk0, xk1);
    jx_subkey(K0, K1, 3u, 2u, uk0, uk1);
    K0 = nk0; K1 = nk1;
    float x, v;
    u32 c0 = xk0, c1 = xk1;
    do {
      u32 t0, t1, s0, s1;
      jx_subkey(c0, c1, 2u, 0u, t0, t1);
      jx_subkey(c0, c1, 2u, 1u, s0, s1);
      c0 = t0; c1 = t1;
      x = normal_from_bits(jx_bits(s0, s1, 1u, 0u));
      v = 1.0f + x * c;
    } while (v <= 0.0f);
    X = x * x;
    V = (v * v) * v;
    U = u01_from_bits(jx_bits(uk0, uk1, 1u, 0u));
  }
  const float sample = d * V;
  const float boost = boost_mask ? 1.0f : powf(u_boost, 1.0f / alpha_orig);
  return sample * boost;
}

__device__ inline float sigm(float x) { return 1.0f / (1.0f + expf(-x)); }
__device__ inline float softplusf(float x) { return fmaxf(x, 0.0f) + log1pf(expf(-fabsf(x))); }

// cross-lane broadcast on the VALU pipe (not DS): v_readlane -> SGPR (ctx kernel)
__device__ inline float rl_f(float v, int l) {
  return __int_as_float(__builtin_amdgcn_readlane(__float_as_int(v), l));
}

// ---------------- workspace layout (floats) ----------------
enum : size_t {
  OFF_INP  = 0,
  OFF_CT   = OFF_INP + (size_t)NB * TM1 * NIN,
  OFF_TS   = OFF_CT + (size_t)NB * CTX,
  OFF_LTS  = OFF_TS + NB,
  OFF_DF   = OFF_LTS + NB,
  OFF_LOC  = OFF_DF + (size_t)NB * CTX,
  OFF_SC   = OFF_LOC + (size_t)NB * CTX,
  OFF_H0F  = OFF_SC + (size_t)NB * CTX,
  OFF_C0F  = OFF_H0F + (size_t)NB * HID,
  OFF_H1F  = OFF_C0F + (size_t)NB * HID,
  OFF_C1F  = OFF_H1F + (size_t)NB * HID,
  OFF_YH   = OFF_C1F + (size_t)NB * HID,
  OFF_WTX  = OFF_YH + (size_t)RTOT * TM1,     // Wih0^T padded [16][256] (ctx kernel)
  OFF_WT00 = OFF_WTX + 4096,                  // Whh0^T [64][256]
  OFF_WT10 = OFF_WT00 + 16384,                // Wih1^T [64][256]
  OFF_WT11 = OFF_WT10 + 16384,                // Whh1^T [64][256]
  OFF_WH   = OFF_WT11 + 16384,                // fp16 MFMA-fragment weights, 53248 halves
  OFF_RND  = OFF_WH + 26624,                  // decode randoms [NSTEP][RTOT][4]
  WS_FLOATS = OFF_RND + (size_t)NSTEP * RTOT * 4
};

// fp16 weight blob segment offsets (in halves)
#define WH_X   0        // layer0 x-part: 16 nt x (32 lanes x 8 halves) 16x16x32 B-frags, k<16 only
#define WH_00  4096     // layer0 h-part: 16 nt x 2 kchunk x (64 x 8)   16x16x32 B-frags
#define WH_10  20480    // layer1 h0-part
#define WH_11  36864    // layer1 h1-part
#define WH_TOT 53248

// ---------------- kernel 0a: transpose weights (fp32, ctx kernel) -----------
__global__ void __launch_bounds__(256) wtrans_kernel(
    const float* __restrict__ Wih0, const float* __restrict__ Whh0,
    const float* __restrict__ Wih1, const float* __restrict__ Whh1,
    float* __restrict__ WTx, float* __restrict__ WT00,
    float* __restrict__ WT10, float* __restrict__ WT11)
{
  const int i = blockIdx.x * 256 + threadIdx.x;   // < 53248
  if (i < 4096) {
    const int k = i >> 8, g = i & 255;
    WTx[i] = (k < 15) ? Wih0[g * 15 + k] : 0.0f;
  } else if (i < 4096 + 16384) {
    const int j = i - 4096, k = j >> 8, g = j & 255;
    WT00[j] = Whh0[g * 64 + k];
  } else if (i < 4096 + 32768) {
    const int j = i - 4096 - 16384, k = j >> 8, g = j & 255;
    WT10[j] = Wih1[g * 64 + k];
  } else {
    const int j = i - 4096 - 32768, k = j >> 8, g = j & 255;
    WT11[j] = Whh1[g * 64 + k];
  }
}

// ---------------- kernel 0a2: fp16 MFMA B-fragment weights for decode --------
// All fragments use the verified shape 16x16x32 (m89/m97 family):
//  h-part:  lane l holds B[k=kc*32+(l>>4)*8+e][n=nt*16+(l&15)], e=0..7 (16B/lane)
//  x-part:  K=32 zero-padded; only lanes 0..31 (k<16) carry real weights.
__global__ void __launch_bounds__(256) wh_kernel(
    const float* __restrict__ Wih0, const float* __restrict__ Whh0,
    const float* __restrict__ Wih1, const float* __restrict__ Whh1,
    f16* __restrict__ WH)
{
  const int j = blockIdx.x * 256 + threadIdx.x;   // < 53248
  if (j < WH_00) {
    const int nt = j >> 8, rem = j & 255;
    const int l = rem >> 3, e = rem & 7;          // l = 0..31
    const int g = nt * 16 + (l & 15);
    const int k = (l >> 4) * 8 + e;               // k = 0..15
    WH[j] = (f16)((k < 15) ? Wih0[g * 15 + k] : 0.0f);
  } else {
    const float* W; int q;
    if (j < WH_10)      { W = Whh0; q = j - WH_00; }
    else if (j < WH_11) { W = Wih1; q = j - WH_10; }
    else                { W = Whh1; q = j - WH_11; }
    const int blk = q >> 9, rem = q & 511;   // blk = nt*2 + kc
    const int l = rem >> 3, e = rem & 7;
    const int nt = blk >> 1, kc = blk & 1;
    const int g = nt * 16 + (l & 15);
    const int k = kc * 32 + (l >> 4) * 8 + e;
    WH[j] = (f16)W[g * 64 + k];
  }
}

// ---------------- kernel 0b: precompute decode randoms -----------------------
__global__ void __launch_bounds__(256) rnd_dec_kernel(
    float* __restrict__ RND, u32 kl0, u32 kl1)
{
  const int i = blockIdx.x * 256 + threadIdx.x;   // < NSTEP*RTOT = 1203200
  const int s = i / RTOT, rg = i - s * RTOT;
  u32 ks0, ks1, skz0, skz1, skg0, skg1;
  tf2x32(kl0, kl1, 0u, (u32)s, ks0, ks1);
  tf2x32(ks0, ks1, 0u, 0u, skz0, skz1);
  tf2x32(ks0, ks1, 0u, 1u, skg0, skg1);
  const float z = normal_from_bits(jx_bits(skz0, skz1, RTOT, (u32)rg));
  u32 gk0, gk1;
  jx_subkey(skg0, skg1, RTOT, (u32)rg, gk0, gk1);
  u32 K0, K1, S0, S1;
  jx_subkey(gk0, gk1, 2u, 0u, K0, K1);
  jx_subkey(gk0, gk1, 2u, 1u, S0, S1);   // boost key, unused (alpha >= 1)
  u32 nk0, nk1, xk0, xk1, uk0, uk1;
  jx_subkey(K0, K1, 3u, 0u, nk0, nk1);
  jx_subkey(K0, K1, 3u, 1u, xk0, xk1);
  jx_subkey(K0, K1, 3u, 2u, uk0, uk1);
  u32 c0 = xk0, c1 = xk1, t0, t1, s0, s1;
  jx_subkey(c0, c1, 2u, 0u, t0, t1);
  jx_subkey(c0, c1, 2u, 1u, s0, s1);
  const float x1 = normal_from_bits(jx_bits(s0, s1, 1u, 0u));
  c0 = t0; c1 = t1;
  jx_subkey(c0, c1, 2u, 0u, t0, t1);
  jx_subkey(c0, c1, 2u, 1u, s0, s1);
  const float x2 = normal_from_bits(jx_bits(s0, s1, 1u, 0u));
  const float U1 = u01_from_bits(jx_bits(uk0, uk1, 1u, 0u));
  float* R = RND + (size_t)i * 4;
  R[0] = z; R[1] = x1; R[2] = x2; R[3] = U1;
}

// ---------------- kernel 1: tscale + feature build ----------------
__global__ void __launch_bounds__(256) prep_kernel(
    const float* __restrict__ X, const float* __restrict__ emb,
    float* __restrict__ inp, float* __restrict__ ct,
    float* __restrict__ tscale, float* __restrict__ ltscale)
{
  const int b = blockIdx.x, t = threadIdx.x;
  __shared__ float red[256];
  __shared__ float ts_sh;
  const float* Xb = X + (size_t)b * LFULL * NCH;
  float p = fabsf(Xb[(28 + t) * NCH]);
  if (t < 80) p += fabsf(Xb[(28 + 256 + t) * NCH]);
  red[t] = p;
  for (int st = 128; st > 0; st >>= 1) { __syncthreads(); if (t < st) red[t] += red[t + st]; }
  __syncthreads();
  if (t == 0) {
    float ts = red[0] / 336.0f;
    ts = fmaxf(ts, 1e-10f);
    tscale[b] = ts; ltscale[b] = logf(ts); ts_sh = ts;
  }
  __syncthreads();
  const float ts = ts_sh;
  const float lts = logf(ts);
  const float ev = emb[0];
  for (int idx = t; idx < TM1 * NIN; idx += 256) {
    const int tt = idx / NIN, f = idx - tt * NIN;
    float val;
    if (f == 0)       val = (tt < CTX) ? Xb[(28 + tt) * NCH] / ts : 0.0f;
    else if (f <= 10) val = (tt < CTX) ? Xb[(28 + tt - c_LAGS[f - 1]) * NCH] / ts : 0.0f;
    else if (f == 11) val = ev;
    else if (f == 12) val = Xb[(28 + tt) * NCH + 2];
    else if (f == 13) val = lts;
    else              val = Xb[(28 + tt) * NCH + 1];
    inp[(size_t)(b * TM1 + tt) * NIN + f] = val;
    if (f == 0 && tt < CTX) ct[b * CTX + tt] = val;
  }
}

// ---------------- kernel 2: context LSTM (unchanged, exact fp32) -------------
__global__ void __launch_bounds__(256) ctx_lstm_kernel(
    const float* __restrict__ inp,
    const float* __restrict__ WTx, const float* __restrict__ WT00,
    const float* __restrict__ WT10, const float* __restrict__ WT11,
    const float* __restrict__ bih0, const float* __restrict__ bhh0,
    const float* __restrict__ bih1, const float* __restrict__ bhh1,
    const float* __restrict__ wdf, const float* __restrict__ bdfp,
    const float* __restrict__ wloc, const float* __restrict__ blocp,
    const float* __restrict__ wsc, const float* __restrict__ bscp,
    float* __restrict__ dfo, float* __restrict__ loco, float* __restrict__ sco,
    float* __restrict__ h0f, float* __restrict__ c0f,
    float* __restrict__ h1f, float* __restrict__ c1f)
{
  const int b = blockIdx.x, t = threadIdx.x;
  const int lane = t & 63, w = t >> 6;
  const int gbase = lane << 2;
  __shared__ __align__(16) float gA[4][256];
  __shared__ __align__(16) float gB[4][256];

  const float bs0 = bih0[lane]       + bhh0[lane];
  const float bs1 = bih0[64 + lane]  + bhh0[64 + lane];
  const float bs2 = bih0[128 + lane] + bhh0[128 + lane];
  const float bs3 = bih0[192 + lane] + bhh0[192 + lane];
  const float bs4 = bih1[lane]       + bhh1[lane];
  const float bs5 = bih1[64 + lane]  + bhh1[64 + lane];
  const float bs6 = bih1[128 + lane] + bhh1[128 + lane];
  const float bs7 = bih1[192 + lane] + bhh1[192 + lane];
  const float wdfv = wdf[lane], wlocv = wloc[lane], wscv = wsc[lane];
  const float bdf = bdfp[0], bloc = blocp[0], bsc = bscp[0];

  float h0r = 0.f, h1r = 0.f, c0r = 0.f, c1r = 0.f;
  const float* inb = inp + (size_t)b * TM1 * NIN;
  const int kx = w * 4;    // x-part k-quarter
  const int kh = w * 16;   // h-part k-quarter

  for (int tt = 0; tt < CTX; tt++) {
    float xr = 0.f;
    if (lane < 15) xr = inb[tt * NIN + lane];

    v2f aA = bc2(0.0f), aB = bc2(0.0f);
#pragma unroll
    for (int kk = 0; kk < 4; kk++) {
      const int k = kx + kk;
      const float4 wv = *(const float4*)&WTx[(k << 8) + gbase];
      v2f wlo, whi; wlo[0] = wv.x; wlo[1] = wv.y; whi[0] = wv.z; whi[1] = wv.w;
      const v2f hk = bc2(rl_f(xr, k));
      aA += wlo * hk; aB += whi * hk;
    }
#pragma unroll
    for (int kk = 0; kk < 16; kk++) {
      const int k = kh + kk;
      const float4 wv = *(const float4*)&WT00[(k << 8) + gbase];
      v2f wlo, whi; wlo[0] = wv.x; wlo[1] = wv.y; whi[0] = wv.z; whi[1] = wv.w;
      const v2f hk = bc2(rl_f(h0r, k));
      aA += wlo * hk; aB += whi * hk;
    }
    {
      float4 gv; gv.x = aA[0]; gv.y = aA[1]; gv.z = aB[0]; gv.w = aB[1];
      *(float4*)&gA[w][gbase] = gv;
    }
    __syncthreads();

    {
      float gi = ((gA[0][lane]       + gA[1][lane])       + gA[2][lane])       + gA[3][lane];
      float gf = ((gA[0][64 + lane]  + gA[1][64 + lane])  + gA[2][64 + lane])  + gA[3][64 + lane];
      float gg = ((gA[0][128 + lane] + gA[1][128 + lane]) + gA[2][128 + lane]) + gA[3][128 + lane];
      float go = ((gA[0][192 + lane] + gA[1][192 + lane]) + gA[2][192 + lane]) + gA[3][192 + lane];
      gi += bs0; gf += bs1; gg += bs2; go += bs3;
      c0r = sigm(gf) * c0r + sigm(gi) * tanhf(gg);
      h0r = sigm(go) * tanhf(c0r);
    }

    aA = bc2(0.0f); aB = bc2(0.0f);
#pragma unroll
    for (int kk = 0; kk < 16; kk++) {
      const int k = kh + kk;
      const float4 wv = *(const float4*)&WT10[(k << 8) + gbase];
      v2f wlo, whi; wlo[0] = wv.x; wlo[1] = wv.y; whi[0] = wv.z; whi[1] = wv.w;
      const v2f hk = bc2(rl_f(h0r, k));
      aA += wlo * hk; aB += whi * hk;
    }
#pragma unroll
    for (int kk = 0; kk < 16; kk++) {
      const int k = kh + kk;
      const float4 wv = *(const float4*)&WT11[(k << 8) + gbase];
      v2f wlo, whi; wlo[0] = wv.x; wlo[1] = wv.y; whi[0] = wv.z; whi[1] = wv.w;
      const v2f hk = bc2(rl_f(h1r, k));
      aA += wlo * hk; aB += whi * hk;
    }
    {
      float4 gv; gv.x = aA[0]; gv.y = aA[1]; gv.z = aB[0]; gv.w = aB[1];
      *(float4*)&gB[w][gbase] = gv;
    }
    __syncthreads();

    {
      float gi = ((gB[0][lane]       + gB[1][lane])       + gB[2][lane])       + gB[3][lane];
      float gf = ((gB[0][64 + lane]  + gB[1][64 + lane])  + gB[2][64 + lane])  + gB[3][64 + lane];
      float gg = ((gB[0][128 + lane] + gB[1][128 + lane]) + gB[2][128 + lane]) + gB[3][128 + lane];
      float go = ((gB[0][192 + lane] + gB[1][192 + lane]) + gB[2][192 + lane]) + gB[3][192 + lane];
      gi += bs4; gf += bs5; gg += bs6; go += bs7;
      c1r = sigm(gf) * c1r + sigm(gi) * tanhf(gg);
      h1r = sigm(go) * tanhf(c1r);
      if (w == 0) {
        float pd = h1r * wdfv, pl = h1r * wlocv, ps = h1r * wscv;
#pragma unroll
        for (int off = 32; off > 0; off >>= 1) {
          pd += __shfl_down(pd, off, 64);
          pl += __shfl_down(pl, off, 64);
          ps += __shfl_down(ps, off, 64);
        }
        if (lane == 0) {
          dfo[b * CTX + tt]  = 2.0f + softplusf(pd + bdf);
          loco[b * CTX + tt] = pl + bloc;
          sco[b * CTX + tt]  = softplusf(ps + bsc);
        }
      }
    }
  }
  if (w == 0) {
    h0f[b * 64 + lane] = h0r; c0f[b * 64 + lane] = c0r;
    h1f[b * 64 + lane] = h1r; c1f[b * 64 + lane] = c1r;
  }
}

// ---------------- kernel 3: context sampling (y_ctx) ----------------
__global__ void __launch_bounds__(256) ctx_sample_kernel(
    const float* __restrict__ df, const float* __restrict__ loc, const float* __restrict__ sc,
    const float* __restrict__ tscale, float* __restrict__ yhat,
    u32 kz0, u32 kz1, u32 kg0, u32 kg1)
{
  const int i = blockIdx.x * 256 + threadIdx.x;
  const int r = i / CTX, t = i - r * CTX;
  const int b = r / NSAMP;
  const float dfv = df[b * CTX + t], lv = loc[b * CTX + t], sv = sc[b * CTX + t];
  const float z = normal_from_bits(jx_bits(kz0, kz1, NCTXS, (u32)i));
  u32 gk0, gk1;
  jx_subkey(kg0, kg1, NCTXS, (u32)i, gk0, gk1);
  const float g = jax_gamma_one(gk0, gk1, dfv * 0.5f);
  const float y = (lv + sv * (z * sqrtf(dfv / (2.0f * g)))) * tscale[b];
  yhat[(size_t)r * TM1 + t] = y;
}

// ---------------- kernel 5: persistent decode (MFMA, spill-free) -------------
// R5: R4's counters showed FETCH_SIZE 3.83 GB + VGPR_Count 128 -> the live
// state (~200 VGPRs: acc 64 + c-state 32 + biases 32 + A-frags + temps) was
// spill-thrashing scratch through HBM.  LDS (160 KB) already caps occupancy at
// 1 block/CU = 2 waves/SIMD, so 256 VGPRs/wave is free: __launch_bounds__(512,2)
// raises the allocator cap (2nd arg = min waves/EU) and removes the spill.
__global__ void __launch_bounds__(512, 2) dec_persist_kernel(
    const float* __restrict__ inp, const float* __restrict__ tscale,
    const f16* __restrict__ WH,
    const float* __restrict__ bih0, const float* __restrict__ bhh0,
    const float* __restrict__ bih1, const float* __restrict__ bhh1,
    const float* __restrict__ wdf, const float* __restrict__ bdfp,
    const float* __restrict__ wloc, const float* __restrict__ blocp,
    const float* __restrict__ wsc, const float* __restrict__ bscp,
    const float* __restrict__ h0f, const float* __restrict__ c0f,
    const float* __restrict__ h1f, const float* __restrict__ c1f,
    const float* __restrict__ ct, const float* __restrict__ RND,
    float* __restrict__ yhat, u32 kl0, u32 kl1)
{
  const int t    = threadIdx.x;
  const int lane = t & 63;
  const int w    = t >> 6;        // wave 0..7
  const int r0   = w * RPW;       // wave's first local row
  const int c16  = lane & 15;     // gate col within tile / A row select
  const int kg   = lane >> 4;     // k-group / D row-group

  __shared__ __align__(16) f16   wgt[WH_TOT];        // 104 KB B-fragment weights
  __shared__ __align__(16) f16   h0h[DROWS * HSTR];  // 18 KB
  __shared__ __align__(16) f16   h1h[DROWS * HSTR];  // 18 KB
  __shared__ __align__(16) f16   xh[DROWS][32];      // 8 KB (slots 15..31 = 0)
  __shared__ __align__(16) f16   hist[DROWS][32];    // 8 KB lag ring
  __shared__ __align__(16) f16   fst[3][NSTEP][4];   // 1.1 KB feature stash
  __shared__ float prevs[DROWS], tsr[DROWS];
  __shared__ float dfL[DROWS], locL[DROWS], scL[DROWS];
  __shared__ unsigned char rsel[DROWS];

  const int base = blockIdx.x * DROWS;
  const int bblo = base / NSAMP;

  // ---- stage all weights once: 13 x (8 waves x 64 lanes x 16B) ----
#pragma unroll
  for (int i = 0; i < 13; i++) {
    const int off = (i * 8 + w) * 512;   // halves
    __builtin_amdgcn_global_load_lds(
        (const __attribute__((address_space(1))) void*)(WH + off + lane * 8),
        (__attribute__((address_space(3))) void*)(wgt + off), 16, 0, 0);
  }

  // ---- per-lane constants: biases / head weights / c-state ----
  float b0[4][4], b1[4][4];
#pragma unroll
  for (int gq = 0; gq < 4; gq++)
#pragma unroll
    for (int tq = 0; tq < 4; tq++) {
      const int g = gq * 64 + tq * 16 + c16;
      b0[gq][tq] = bih0[g] + bhh0[g];
      b1[gq][tq] = bih1[g] + bhh1[g];
    }
  float wd[4], wl[4], wsv[4];
#pragma unroll
  for (int tq = 0; tq < 4; tq++) {
    wd[tq]  = wdf[tq * 16 + c16];
    wl[tq]  = wloc[tq * 16 + c16];
    wsv[tq] = wsc[tq * 16 + c16];
  }
  const float bdf = bdfp[0], bloc = blocp[0], bsc = bscp[0];

  float c0reg[4][4], c1reg[4][4];
#pragma unroll
  for (int rr = 0; rr < 4; rr++) {
    const int row = r0 + kg * 4 + rr;
    const int bb = (base + row) / NSAMP;
#pragma unroll
    for (int tq = 0; tq < 4; tq++) {
      c0reg[rr][tq] = c0f[bb * 64 + tq * 16 + c16];
      c1reg[rr][tq] = c1f[bb * 64 + tq * 16 + c16];
    }
  }

  // ---- h state into LDS (stride HSTR) ----
  for (int idx = t; idx < DROWS * 64; idx += 512) {
    const int row = idx >> 6, hid = idx & 63;
    const int bb = (base + row) / NSAMP;
    h0h[row * HSTR + hid] = (f16)h0f[bb * 64 + hid];
    h1h[row * HSTR + hid] = (f16)h1f[bb * 64 + hid];
  }

  for (int idx = t; idx < DROWS * 28; idx += 512) {
    const int i = idx / 28, k = idx - i * 28;
    const int bb = (base + i) / NSAMP;
    hist[i][31 - k] = (f16)ct[bb * CTX + 335 - k];
  }
  // feature stash: rows of a 128-row block span at most 3 batch indices
  for (int idx = t; idx < 3 * NSTEP * 4; idx += 512) {
    const int sel = idx / (NSTEP * 4), rem = idx - sel * (NSTEP * 4);
    const int s = rem >> 2, f = rem & 3;
    const int bb = min(bblo + sel, NB - 1);
    fst[sel][s][f] = (f16)inp[((size_t)bb * TM1 + CTX + s) * NIN + 11 + f];
  }
  if (t < DROWS) {
    const int rg = base + t;
    prevs[t] = yhat[(size_t)rg * TM1 + 335];
    tsr[t] = tscale[rg / NSAMP];
    for (int j = 15; j < 32; j++) xh[t][j] = (f16)0.0f;  // hard-zero K pad
    rsel[t] = (unsigned char)((rg / NSAMP) - bblo);
  }
  __syncthreads();   // covers weight staging (vmcnt drain) + all init writes

  const int arow = r0 + c16;         // A-fragment row for this lane

  for (int s = 0; s < NSTEP; s++) {
    // ---- prefetch this step's randoms ----
    float rz = 0.f, rx1 = 0.f, rx2 = 0.f, rU = 0.f;
    if (lane < RPW) {
      const float4 R = *(const float4*)(RND + ((size_t)s * RTOT + base + r0 + lane) * 4);
      rz = R.x; rx1 = R.y; rx2 = R.z; rU = R.w;
    }

    // ---- parallel x-build (slots 0..14; 15..31 stay zero) ----
    if (lane < RPW) {
      const int row = r0 + lane;
      const float nv = prevs[row] / tsr[row];
      const f16 nh = (f16)nv;
      xh[row][0] = nh;
      hist[row][s & 31] = nh;
    }
    {
      const int rq = lane >> 2, q = lane & 3;
      const int row = r0 + rq;
#pragma unroll
      for (int p = 0; p < 4; p++) {
        const int sl = 1 + q + p * 4;          // 1..16
        if (sl <= 10) {
          xh[row][sl] = hist[row][(s - c_LAGS[sl - 1]) & 31];
        } else if (sl <= 14) {
          xh[row][sl] = fst[rsel[row]][s][sl - 11];
        }
      }
    }

    // ---- layer 0: A-frags + 48 MFMAs (all 16x16x32_f16) ----
    const half8 ax  = *(const half8*)&xh[arow][kg * 8];
    const half8 a00 = *(const half8*)&h0h[arow * HSTR + kg * 8];
    const half8 a01 = *(const half8*)&h0h[arow * HSTR + 32 + kg * 8];
    floatx4 acc[16];
#pragma unroll
    for (int nt = 0; nt < 16; nt++) {
      floatx4 a = {0.f, 0.f, 0.f, 0.f};
      a = __builtin_amdgcn_mfma_f32_16x16x32_f16(
            ax, *(const half8*)&wgt[WH_X + nt * 256 + lane * 8], a, 0, 0, 0);
      a = __builtin_amdgcn_mfma_f32_16x16x32_f16(
            a00, *(const half8*)&wgt[WH_00 + (nt * 2 + 0) * 512 + lane * 8], a, 0, 0, 0);
      a = __builtin_amdgcn_mfma_f32_16x16x32_f16(
            a01, *(const half8*)&wgt[WH_00 + (nt * 2 + 1) * 512 + lane * 8], a, 0, 0, 0);
      acc[nt] = a;
    }

    // ---- cell 0 (lane-local i/f/g/o per hid) ----
#pragma unroll
    for (int rr = 0; rr < 4; rr++) {
      const int row = r0 + kg * 4 + rr;
#pragma unroll
      for (int tq = 0; tq < 4; tq++) {
        const float gi = acc[tq][rr]      + b0[0][tq];
        const float gf = acc[4 + tq][rr]  + b0[1][tq];
        const float gg = acc[8 + tq][rr]  + b0[2][tq];
        const float go = acc[12 + tq][rr] + b0[3][tq];
        float cc = c0reg[rr][tq];
        cc = sigm(gf) * cc + sigm(gi) * tanhf(gg);
        c0reg[rr][tq] = cc;
        h0h[row * HSTR + tq * 16 + c16] = (f16)(sigm(go) * tanhf(cc));
      }
    }

    // ---- layer 1: A-frags + 64 MFMAs ----
    const half8 a10a = *(const half8*)&h0h[arow * HSTR + kg * 8];
    const half8 a10b = *(const half8*)&h0h[arow * HSTR + 32 + kg * 8];
    const half8 a11a = *(const half8*)&h1h[arow * HSTR + kg * 8];
    const half8 a11b = *(const half8*)&h1h[arow * HSTR + 32 + kg * 8];
#pragma unroll
    for (int nt = 0; nt < 16; nt++) {
      floatx4 a = {0.f, 0.f, 0.f, 0.f};
      a = __builtin_amdgcn_mfma_f32_16x16x32_f16(
            a10a, *(const half8*)&wgt[WH_10 + (nt * 2 + 0) * 512 + lane * 8], a, 0, 0, 0);
      a = __builtin_amdgcn_mfma_f32_16x16x32_f16(
            a10b, *(const half8*)&wgt[WH_10 + (nt * 2 + 1) * 512 + lane * 8], a, 0, 0, 0);
      a = __builtin_amdgcn_mfma_f32_16x16x32_f16(
            a11a, *(const half8*)&wgt[WH_11 + (nt * 2 + 0) * 512 + lane * 8], a, 0, 0, 0);
      a = __builtin_amdgcn_mfma_f32_16x16x32_f16(
            a11b, *(const half8*)&wgt[WH_11 + (nt * 2 + 1) * 512 + lane * 8], a, 0, 0, 0);
      acc[nt] = a;
    }

    // ---- cell 1 + head partials ----
    float pd[4], pl[4], ps[4];
#pragma unroll
    for (int rr = 0; rr < 4; rr++) { pd[rr] = 0.f; pl[rr] = 0.f; ps[rr] = 0.f; }
#pragma unroll
    for (int rr = 0; rr < 4; rr++) {
      const int row = r0 + kg * 4 + rr;
#pragma unroll
      for (int tq = 0; tq < 4; tq++) {
        const float gi = acc[tq][rr]      + b1[0][tq];
        const float gf = acc[4 + tq][rr]  + b1[1][tq];
        const float gg = acc[8 + tq][rr]  + b1[2][tq];
        const float go = acc[12 + tq][rr] + b1[3][tq];
        float cc = c1reg[rr][tq];
        cc = sigm(gf) * cc + sigm(gi) * tanhf(gg);
        c1reg[rr][tq] = cc;
        const float h1v = sigm(go) * tanhf(cc);
        h1h[row * HSTR + tq * 16 + c16] = (f16)h1v;
        pd[rr] += h1v * wd[tq];
        pl[rr] += h1v * wl[tq];
        ps[rr] += h1v * wsv[tq];
      }
    }
    // reduce across the 16 cols (lanes share kg within width-16 groups)
#pragma unroll
    for (int rr = 0; rr < 4; rr++) {
#pragma unroll
      for (int off = 8; off >= 1; off >>= 1) {
        pd[rr] += __shfl_xor(pd[rr], off, 16);
        pl[rr] += __shfl_xor(pl[rr], off, 16);
        ps[rr] += __shfl_xor(ps[rr], off, 16);
      }
    }
    if (c16 == 0) {
#pragma unroll
      for (int rr = 0; rr < 4; rr++) {
        const int row = r0 + kg * 4 + rr;
        dfL[row]  = 2.0f + softplusf(pd[rr] + bdf);
        locL[row] = pl[rr] + bloc;
        scL[row]  = softplusf(ps[rr] + bsc);
      }
    }

    // ---- sample (one lane per row, 16 rows in parallel) ----
    if (lane < RPW) {
      const int row = r0 + lane, rg = base + row;
      const float dfv = dfL[row], lv = locL[row], scv = scL[row];
      const float z = rz;
      const float alpha = dfv * 0.5f;
      float gam;
      {
#pragma clang fp contract(off)
        const float d = alpha - 0.33333334f;
        const float c = 0.33333334f / sqrtf(d);
        float x = rx1;
        float v = 1.0f + x * c;
        bool ok = true;
        if (v <= 0.0f) { x = rx2; v = 1.0f + x * c; ok = (v > 0.0f); }
        const float X = x * x;
        const float V = (v * v) * v;
        const float U = rU;
        bool accept = false;
        if (ok) {
          if (!(U >= 1.0f - 0.0331f * (X * X))) accept = true;
          else if (!(logf(U) >= 0.5f * X + d * ((1.0f - V) + logf(V)))) accept = true;
        }
        if (accept) {
          gam = d * V;
        } else {
          u32 ks0, ks1, skg0, skg1, gk0, gk1;
          tf2x32(kl0, kl1, 0u, (u32)s, ks0, ks1);
          tf2x32(ks0, ks1, 0u, 1u, skg0, skg1);
          jx_subkey(skg0, skg1, RTOT, (u32)rg, gk0, gk1);
          gam = jax_gamma_one(gk0, gk1, alpha);
        }
      }
      const float y = (lv + scv * (z * sqrtf(dfv / (2.0f * gam)))) * tsr[row];
      yhat[(size_t)rg * TM1 + CTX + s] = y;
      prevs[row] = y;
    }
  }
}

// ---------------- kernel 6: median over 100 samples per (b,t) ----------------
__global__ void __launch_bounds__(256) median_kernel(
    const float* __restrict__ yhat, float* __restrict__ out)
{
  __shared__ float vals[4][100];
  const int wave = threadIdx.x >> 6, lane = threadIdx.x & 63;
  const int cell = blockIdx.x * 4 + wave;
  const int b = cell / TM1, t = cell - b * TM1;
  const float* basep = yhat + (size_t)b * NSAMP * TM1 + t;
  const float v1 = basep[(size_t)lane * TM1];
  vals[wave][lane] = v1;
  float v2 = 0.f;
  if (lane < 36) { v2 = basep[(size_t)(64 + lane) * TM1]; vals[wave][64 + lane] = v2; }
  __syncthreads();
  int cl1 = 0, ce1 = 0, cl2 = 0, ce2 = 0;
  for (int jj = 0; jj < 100; jj++) {
    const float w = vals[wave][jj];
    cl1 += (w < v1); ce1 += (w == v1);
    cl2 += (w < v2); ce2 += (w == v2);
  }
  if (cl1 <= 49 && 49 < cl1 + ce1) out[cell] = v1;
  if (lane < 36 && cl2 <= 49 && 49 < cl2 + ce2) out[cell] = v2;
}

// ---------------- launch ----------------
extern "C" void kernel_launch(void* const* d_in, const int* in_sizes, int n_in,
                              void* d_out, int out_size, void* d_ws, size_t ws_size,
                              hipStream_t stream) {
  (void)in_sizes; (void)n_in; (void)out_size; (void)ws_size;
  const float* X     = (const float*)d_in[0];
  const float* Wih0  = (const float*)d_in[2];
  const float* Whh0  = (const float*)d_in[3];
  const float* bih0  = (const float*)d_in[4];
  const float* bhh0  = (const float*)d_in[5];
  const float* Wih1  = (const float*)d_in[6];
  const float* Whh1  = (const float*)d_in[7];
  const float* bih1  = (const float*)d_in[8];
  const float* bhh1  = (const float*)d_in[9];
  const float* wdf   = (const float*)d_in[10];
  const float* bdf   = (const float*)d_in[11];
  const float* wloc  = (const float*)d_in[12];
  const float* bloc  = (const float*)d_in[13];
  const float* wsc   = (const float*)d_in[14];
  const float* bsc   = (const float*)d_in[15];
  const float* emb   = (const float*)d_in[16];

  float* wsf = (float*)d_ws;
  float* inp  = wsf + OFF_INP;
  float* ct   = wsf + OFF_CT;
  float* ts   = wsf + OFF_TS;
  float* lts  = wsf + OFF_LTS;
  float* dfp  = wsf + OFF_DF;
  float* locp = wsf + OFF_LOC;
  float* scp  = wsf + OFF_SC;
  float* h0f  = wsf + OFF_H0F;
  float* c0f  = wsf + OFF_C0F;
  float* h1f  = wsf + OFF_H1F;
  float* c1f  = wsf + OFF_C1F;
  float* yhat = wsf + OFF_YH;
  float* wtx  = wsf + OFF_WTX;
  float* wt00 = wsf + OFF_WT00;
  float* wt10 = wsf + OFF_WT10;
  float* wt11 = wsf + OFF_WT11;
  f16*   wh   = (f16*)(wsf + OFF_WH);
  float* rnd  = wsf + OFF_RND;

  const u32 key0 = 0u, key1 = 42u;
  u32 kc0, kc1, kl0, kl1;
  jx_subkey(key0, key1, 2u, 0u, kc0, kc1);
  jx_subkey(key0, key1, 2u, 1u, kl0, kl1);
  u32 kz0, kz1, kg0, kg1;
  jx_subkey(kc0, kc1, 2u, 0u, kz0, kz1);
  jx_subkey(kc0, kc1, 2u, 1u, kg0, kg1);

  wtrans_kernel<<<208, 256, 0, stream>>>(Wih0, Whh0, Wih1, Whh1, wtx, wt00, wt10, wt11);
  wh_kernel<<<208, 256, 0, stream>>>(Wih0, Whh0, Wih1, Whh1, wh);
  rnd_dec_kernel<<<(NSTEP * RTOT) / 256, 256, 0, stream>>>(rnd, kl0, kl1);
  prep_kernel<<<NB, 256, 0, stream>>>(X, emb, inp, ct, ts, lts);
  ctx_lstm_kernel<<<NB, 256, 0, stream>>>(inp, wtx, wt00, wt10, wt11,
                                          bih0, bhh0, bih1, bhh1,
                                          wdf, bdf, wloc, bloc, wsc, bsc,
                                          dfp, locp, scp, h0f, c0f, h1f, c1f);
  ctx_sample_kernel<<<NCTXS / 256, 256, 0, stream>>>(dfp, locp, scp, ts, yhat, kz0, kz1, kg0, kg1);
  dec_persist_kernel<<<DBLOCKS, 512, 0, stream>>>(inp, ts, wh,
                                                  bih0, bhh0, bih1, bhh1,
                                                  wdf, bdf, wloc, bloc, wsc, bsc,
                                                  h0f, c0f, h1f, c1f, ct, rnd, yhat, kl0, kl1);
  median_kernel<<<(NB * TM1) / 4, 256, 0, stream>>>(yhat, (float*)d_out);
}

// Round 7
// 2951.414 us; speedup vs baseline: 1.2240x; 1.2240x over previous
//
#include <hip/hip_runtime.h>
#include <stdint.h>
#include <stddef.h>

typedef uint32_t u32;
typedef float v2f __attribute__((ext_vector_type(2)));
typedef _Float16 f16;
typedef f16 half8 __attribute__((ext_vector_type(8)));
typedef float floatx4 __attribute__((ext_vector_type(4)));

// ---------------- problem constants (fixed by reference file) ----------------
#define NB    256      // batch B
#define LFULL 412      // L
#define NCH   3        // C
#define CTX   336      // context_length
#define NSAMP 100      // n_samples
#define TM1   383      // T-1 (T = L - MAX_LAG = 384)
#define HID   64
#define NIN   15
#define RTOT  25600    // NB*NSAMP
#define NCTXS 8601600u // RTOT*CTX
#define NSTEP 47       // H-1

#define DROWS   128    // rows per persistent decode block (16 per wave, 8 waves)
#define RPW     16     // rows per wave
#define DBLOCKS (RTOT / DROWS)  // 200 -> 1 dispatch round on 256 CUs

#define HSTR    72     // h-array LDS stride in halves (144 B, 16B-aligned, bank-spread)

#define JAX_PARTITIONABLE 1

__device__ const int c_LAGS[10] = {1,2,3,4,5,6,7,14,21,28};

__device__ inline v2f bc2(float x) { v2f r; r[0] = x; r[1] = x; return r; }

// ---------------- threefry2x32 (matches jax._src.prng) ----------------
__host__ __device__ inline void tf2x32(u32 k0, u32 k1, u32 x0, u32 x1, u32& o0, u32& o1) {
  const u32 ks2 = k0 ^ k1 ^ 0x1BD11BDAu;
#define TFR(r) { x0 += x1; x1 = (x1 << (r)) | (x1 >> (32 - (r))); x1 ^= x0; }
  x0 += k0; x1 += k1;
  TFR(13) TFR(15) TFR(26) TFR(6)
  x0 += k1; x1 += ks2 + 1u;
  TFR(17) TFR(29) TFR(16) TFR(24)
  x0 += ks2; x1 += k0 + 2u;
  TFR(13) TFR(15) TFR(26) TFR(6)
  x0 += k0; x1 += k1 + 3u;
  TFR(17) TFR(29) TFR(16) TFR(24)
  x0 += k1; x1 += ks2 + 4u;
  TFR(13) TFR(15) TFR(26) TFR(6)
  x0 += ks2; x1 += k0 + 5u;
#undef TFR
  o0 = x0; o1 = x1;
}

__host__ __device__ inline u32 split_word_legacy(u32 k0, u32 k1, u32 n, u32 j) {
  u32 o0, o1;
  if (j < n) { tf2x32(k0, k1, j, n + j, o0, o1); return o0; }
  tf2x32(k0, k1, j - n, j, o0, o1); return o1;
}

__host__ __device__ inline void jx_subkey(u32 k0, u32 k1, u32 n, u32 i, u32& s0, u32& s1) {
#if JAX_PARTITIONABLE
  (void)n; tf2x32(k0, k1, 0u, i, s0, s1);
#else
  s0 = split_word_legacy(k0, k1, n, 2u * i);
  s1 = split_word_legacy(k0, k1, n, 2u * i + 1u);
#endif
}

__device__ inline u32 jx_bits(u32 k0, u32 k1, u32 n, u32 i) {
#if JAX_PARTITIONABLE
  (void)n; u32 o0, o1; tf2x32(k0, k1, 0u, i, o0, o1); return o0 ^ o1;
#else
  u32 o0, o1;
  if (n == 1u) { tf2x32(k0, k1, 0u, 0u, o0, o1); return o0; }
  const u32 h = n >> 1;
  if (i < h) { tf2x32(k0, k1, i, h + i, o0, o1); return o0; }
  tf2x32(k0, k1, i - h, i, o0, o1); return o1;
#endif
}

// ---------------- JAX-exact float transforms ----------------
__device__ inline float jax_erfinv(float x) {
#pragma clang fp contract(off)
  float w = -log1pf(-x * x);
  float p;
  if (w < 5.0f) {
    w = w - 2.5f;
    p = 2.81022636e-08f;
    p = 3.43273939e-07f + p * w;
    p = -3.5233877e-06f + p * w;
    p = -4.39150654e-06f + p * w;
    p = 0.00021858087f + p * w;
    p = -0.00125372503f + p * w;
    p = -0.00417768164f + p * w;
    p = 0.246640727f + p * w;
    p = 1.50140941f + p * w;
  } else {
    w = sqrtf(w) - 3.0f;
    p = -0.000200214257f;
    p = 0.000100950558f + p * w;
    p = 0.00134934322f + p * w;
    p = -0.00367342844f + p * w;
    p = 0.00573950773f + p * w;
    p = -0.0076224613f + p * w;
    p = 0.00943887047f + p * w;
    p = 1.00167406f + p * w;
    p = 2.83297682f + p * w;
  }
  return p * x;
}

__device__ inline float u01_from_bits(u32 bits) {
  return __uint_as_float((bits >> 9) | 0x3f800000u) - 1.0f;
}

__device__ inline float normal_from_bits(u32 bits) {
#pragma clang fp contract(off)
  const float lo = -0.99999994f;
  const float u = u01_from_bits(bits);
  float r = u * 2.0f + lo;
  r = fmaxf(lo, r);
  return 1.41421356f * jax_erfinv(r);
}

__device__ float jax_gamma_one(u32 k0, u32 k1, float alpha) {
#pragma clang fp contract(off)
  const bool boost_mask = (alpha >= 1.0f);
  const float alpha_orig = alpha;
  const float a = boost_mask ? alpha : (alpha + 1.0f);
  const float d = a - 0.33333334f;
  const float c = 0.33333334f / sqrtf(d);
  u32 K0, K1, S0, S1;
  jx_subkey(k0, k1, 2u, 0u, K0, K1);
  jx_subkey(k0, k1, 2u, 1u, S0, S1);
  float u_boost = 1.0f;
  if (!boost_mask) u_boost = u01_from_bits(jx_bits(S0, S1, 1u, 0u));
  float X = 0.0f, V = 1.0f, U = 2.0f;
  while (true) {
    if (!(U >= 1.0f - 0.0331f * (X * X))) break;
    if (!(logf(U) >= 0.5f * X + d * ((1.0f - V) + logf(V)))) break;
    u32 nk0, nk1, xk0, xk1, uk0, uk1;
    jx_subkey(K0, K1, 3u, 0u, nk0, nk1);
    jx_subkey(K0, K1, 3u, 1u, xk0, xk1);
    jx_subkey(K0, K1, 3u, 2u, uk0, uk1);
    K0 = nk0; K1 = nk1;
    float x, v;
    u32 c0 = xk0, c1 = xk1;
    do {
      u32 t0, t1, s0, s1;
      jx_subkey(c0, c1, 2u, 0u, t0, t1);
      jx_subkey(c0, c1, 2u, 1u, s0, s1);
      c0 = t0; c1 = t1;
      x = normal_from_bits(jx_bits(s0, s1, 1u, 0u));
      v = 1.0f + x * c;
    } while (v <= 0.0f);
    X = x * x;
    V = (v * v) * v;
    U = u01_from_bits(jx_bits(uk0, uk1, 1u, 0u));
  }
  const float sample = d * V;
  const float boost = boost_mask ? 1.0f : powf(u_boost, 1.0f / alpha_orig);
  return sample * boost;
}

__device__ inline float sigm(float x) { return 1.0f / (1.0f + expf(-x)); }
__device__ inline float softplusf(float x) { return fmaxf(x, 0.0f) + log1pf(expf(-fabsf(x))); }

// cross-lane broadcast on the VALU pipe (not DS): v_readlane -> SGPR (ctx kernel)
__device__ inline float rl_f(float v, int l) {
  return __int_as_float(__builtin_amdgcn_readlane(__float_as_int(v), l));
}

// ---------------- workspace layout (floats) ----------------
enum : size_t {
  OFF_INP  = 0,
  OFF_CT   = OFF_INP + (size_t)NB * TM1 * NIN,
  OFF_TS   = OFF_CT + (size_t)NB * CTX,
  OFF_LTS  = OFF_TS + NB,
  OFF_DF   = OFF_LTS + NB,
  OFF_LOC  = OFF_DF + (size_t)NB * CTX,
  OFF_SC   = OFF_LOC + (size_t)NB * CTX,
  OFF_H0F  = OFF_SC + (size_t)NB * CTX,
  OFF_C0F  = OFF_H0F + (size_t)NB * HID,
  OFF_H1F  = OFF_C0F + (size_t)NB * HID,
  OFF_C1F  = OFF_H1F + (size_t)NB * HID,
  OFF_YH   = OFF_C1F + (size_t)NB * HID,
  OFF_WTX  = OFF_YH + (size_t)RTOT * TM1,     // Wih0^T padded [16][256] (ctx kernel)
  OFF_WT00 = OFF_WTX + 4096,                  // Whh0^T [64][256]
  OFF_WT10 = OFF_WT00 + 16384,                // Wih1^T [64][256]
  OFF_WT11 = OFF_WT10 + 16384,                // Whh1^T [64][256]
  OFF_WH   = OFF_WT11 + 16384,                // fp16 MFMA-fragment weights, 53248 halves
  OFF_RND  = OFF_WH + 26624,                  // decode randoms [NSTEP][RTOT][4]
  WS_FLOATS = OFF_RND + (size_t)NSTEP * RTOT * 4
};

// fp16 weight blob segment offsets (in halves)
#define WH_X   0        // layer0 x-part: 16 nt x (32 lanes x 8 halves); k=15 = bias0 (x[15]=1)
#define WH_00  4096     // layer0 h-part: 16 nt x 2 kchunk x (64 x 8)   16x16x32 B-frags
#define WH_10  20480    // layer1 h0-part
#define WH_11  36864    // layer1 h1-part
#define WH_TOT 53248

// ---------------- kernel 0a: transpose weights (fp32, ctx kernel) -----------
__global__ void __launch_bounds__(256) wtrans_kernel(
    const float* __restrict__ Wih0, const float* __restrict__ Whh0,
    const float* __restrict__ Wih1, const float* __restrict__ Whh1,
    float* __restrict__ WTx, float* __restrict__ WT00,
    float* __restrict__ WT10, float* __restrict__ WT11)
{
  const int i = blockIdx.x * 256 + threadIdx.x;   // < 53248
  if (i < 4096) {
    const int k = i >> 8, g = i & 255;
    WTx[i] = (k < 15) ? Wih0[g * 15 + k] : 0.0f;
  } else if (i < 4096 + 16384) {
    const int j = i - 4096, k = j >> 8, g = j & 255;
    WT00[j] = Whh0[g * 64 + k];
  } else if (i < 4096 + 32768) {
    const int j = i - 4096 - 16384, k = j >> 8, g = j & 255;
    WT10[j] = Wih1[g * 64 + k];
  } else {
    const int j = i - 4096 - 32768, k = j >> 8, g = j & 255;
    WT11[j] = Whh1[g * 64 + k];
  }
}

// ---------------- kernel 0a2: fp16 MFMA B-fragment weights for decode --------
// All fragments use the verified shape 16x16x32 (m89/m97 family):
//  h-part:  lane l holds B[k=kc*32+(l>>4)*8+e][n=nt*16+(l&15)], e=0..7 (16B/lane)
//  x-part:  K=32 zero-padded; lanes 0..31 carry k=0..15.  R6: the k==15 slot
//           (previously 0) now holds the layer-0 bias (bih0+bhh0), paired
//           with xh[row][15]=1.0 -> x-MFMA emits Wx*x + b0 (b0 regs deleted).
__global__ void __launch_bounds__(256) wh_kernel(
    const float* __restrict__ Wih0, const float* __restrict__ Whh0,
    const float* __restrict__ Wih1, const float* __restrict__ Whh1,
    const float* __restrict__ bih0, const float* __restrict__ bhh0,
    f16* __restrict__ WH)
{
  const int j = blockIdx.x * 256 + threadIdx.x;   // < 53248
  if (j < WH_00) {
    const int nt = j >> 8, rem = j & 255;
    const int l = rem >> 3, e = rem & 7;          // l = 0..31
    const int g = nt * 16 + (l & 15);
    const int k = (l >> 4) * 8 + e;               // k = 0..15
    WH[j] = (f16)((k < 15) ? Wih0[g * 15 + k] : (bih0[g] + bhh0[g]));
  } else {
    const float* W; int q;
    if (j < WH_10)      { W = Whh0; q = j - WH_00; }
    else if (j < WH_11) { W = Wih1; q = j - WH_10; }
    else                { W = Whh1; q = j - WH_11; }
    const int blk = q >> 9, rem = q & 511;   // blk = nt*2 + kc
    const int l = rem >> 3, e = rem & 7;
    const int nt = blk >> 1, kc = blk & 1;
    const int g = nt * 16 + (l & 15);
    const int k = kc * 32 + (l >> 4) * 8 + e;
    WH[j] = (f16)W[g * 64 + k];
  }
}

// ---------------- kernel 0b: precompute decode randoms -----------------------
__global__ void __launch_bounds__(256) rnd_dec_kernel(
    float* __restrict__ RND, u32 kl0, u32 kl1)
{
  const int i = blockIdx.x * 256 + threadIdx.x;   // < NSTEP*RTOT = 1203200
  const int s = i / RTOT, rg = i - s * RTOT;
  u32 ks0, ks1, skz0, skz1, skg0, skg1;
  tf2x32(kl0, kl1, 0u, (u32)s, ks0, ks1);
  tf2x32(ks0, ks1, 0u, 0u, skz0, skz1);
  tf2x32(ks0, ks1, 0u, 1u, skg0, skg1);
  const float z = normal_from_bits(jx_bits(skz0, skz1, RTOT, (u32)rg));
  u32 gk0, gk1;
  jx_subkey(skg0, skg1, RTOT, (u32)rg, gk0, gk1);
  u32 K0, K1, S0, S1;
  jx_subkey(gk0, gk1, 2u, 0u, K0, K1);
  jx_subkey(gk0, gk1, 2u, 1u, S0, S1);   // boost key, unused (alpha >= 1)
  u32 nk0, nk1, xk0, xk1, uk0, uk1;
  jx_subkey(K0, K1, 3u, 0u, nk0, nk1);
  jx_subkey(K0, K1, 3u, 1u, xk0, xk1);
  jx_subkey(K0, K1, 3u, 2u, uk0, uk1);
  u32 c0 = xk0, c1 = xk1, t0, t1, s0, s1;
  jx_subkey(c0, c1, 2u, 0u, t0, t1);
  jx_subkey(c0, c1, 2u, 1u, s0, s1);
  const float x1 = normal_from_bits(jx_bits(s0, s1, 1u, 0u));
  c0 = t0; c1 = t1;
  jx_subkey(c0, c1, 2u, 0u, t0, t1);
  jx_subkey(c0, c1, 2u, 1u, s0, s1);
  const float x2 = normal_from_bits(jx_bits(s0, s1, 1u, 0u));
  const float U1 = u01_from_bits(jx_bits(uk0, uk1, 1u, 0u));
  float* R = RND + (size_t)i * 4;
  R[0] = z; R[1] = x1; R[2] = x2; R[3] = U1;
}

// ---------------- kernel 1: tscale + feature build ----------------
__global__ void __launch_bounds__(256) prep_kernel(
    const float* __restrict__ X, const float* __restrict__ emb,
    float* __restrict__ inp, float* __restrict__ ct,
    float* __restrict__ tscale, float* __restrict__ ltscale)
{
  const int b = blockIdx.x, t = threadIdx.x;
  __shared__ float red[256];
  __shared__ float ts_sh;
  const float* Xb = X + (size_t)b * LFULL * NCH;
  float p = fabsf(Xb[(28 + t) * NCH]);
  if (t < 80) p += fabsf(Xb[(28 + 256 + t) * NCH]);
  red[t] = p;
  for (int st = 128; st > 0; st >>= 1) { __syncthreads(); if (t < st) red[t] += red[t + st]; }
  __syncthreads();
  if (t == 0) {
    float ts = red[0] / 336.0f;
    ts = fmaxf(ts, 1e-10f);
    tscale[b] = ts; ltscale[b] = logf(ts); ts_sh = ts;
  }
  __syncthreads();
  const float ts = ts_sh;
  const float lts = logf(ts);
  const float ev = emb[0];
  for (int idx = t; idx < TM1 * NIN; idx += 256) {
    const int tt = idx / NIN, f = idx - tt * NIN;
    float val;
    if (f == 0)       val = (tt < CTX) ? Xb[(28 + tt) * NCH] / ts : 0.0f;
    else if (f <= 10) val = (tt < CTX) ? Xb[(28 + tt - c_LAGS[f - 1]) * NCH] / ts : 0.0f;
    else if (f == 11) val = ev;
    else if (f == 12) val = Xb[(28 + tt) * NCH + 2];
    else if (f == 13) val = lts;
    else              val = Xb[(28 + tt) * NCH + 1];
    inp[(size_t)(b * TM1 + tt) * NIN + f] = val;
    if (f == 0 && tt < CTX) ct[b * CTX + tt] = val;
  }
}

// ---------------- kernel 2: context LSTM (unchanged, exact fp32) -------------
__global__ void __launch_bounds__(256) ctx_lstm_kernel(
    const float* __restrict__ inp,
    const float* __restrict__ WTx, const float* __restrict__ WT00,
    const float* __restrict__ WT10, const float* __restrict__ WT11,
    const float* __restrict__ bih0, const float* __restrict__ bhh0,
    const float* __restrict__ bih1, const float* __restrict__ bhh1,
    const float* __restrict__ wdf, const float* __restrict__ bdfp,
    const float* __restrict__ wloc, const float* __restrict__ blocp,
    const float* __restrict__ wsc, const float* __restrict__ bscp,
    float* __restrict__ dfo, float* __restrict__ loco, float* __restrict__ sco,
    float* __restrict__ h0f, float* __restrict__ c0f,
    float* __restrict__ h1f, float* __restrict__ c1f)
{
  const int b = blockIdx.x, t = threadIdx.x;
  const int lane = t & 63, w = t >> 6;
  const int gbase = lane << 2;
  __shared__ __align__(16) float gA[4][256];
  __shared__ __align__(16) float gB[4][256];

  const float bs0 = bih0[lane]       + bhh0[lane];
  const float bs1 = bih0[64 + lane]  + bhh0[64 + lane];
  const float bs2 = bih0[128 + lane] + bhh0[128 + lane];
  const float bs3 = bih0[192 + lane] + bhh0[192 + lane];
  const float bs4 = bih1[lane]       + bhh1[lane];
  const float bs5 = bih1[64 + lane]  + bhh1[64 + lane];
  const float bs6 = bih1[128 + lane] + bhh1[128 + lane];
  const float bs7 = bih1[192 + lane] + bhh1[192 + lane];
  const float wdfv = wdf[lane], wlocv = wloc[lane], wscv = wsc[lane];
  const float bdf = bdfp[0], bloc = blocp[0], bsc = bscp[0];

  float h0r = 0.f, h1r = 0.f, c0r = 0.f, c1r = 0.f;
  const float* inb = inp + (size_t)b * TM1 * NIN;
  const int kx = w * 4;    // x-part k-quarter
  const int kh = w * 16;   // h-part k-quarter

  for (int tt = 0; tt < CTX; tt++) {
    float xr = 0.f;
    if (lane < 15) xr = inb[tt * NIN + lane];

    v2f aA = bc2(0.0f), aB = bc2(0.0f);
#pragma unroll
    for (int kk = 0; kk < 4; kk++) {
      const int k = kx + kk;
      const float4 wv = *(const float4*)&WTx[(k << 8) + gbase];
      v2f wlo, whi; wlo[0] = wv.x; wlo[1] = wv.y; whi[0] = wv.z; whi[1] = wv.w;
      const v2f hk = bc2(rl_f(xr, k));
      aA += wlo * hk; aB += whi * hk;
    }
#pragma unroll
    for (int kk = 0; kk < 16; kk++) {
      const int k = kh + kk;
      const float4 wv = *(const float4*)&WT00[(k << 8) + gbase];
      v2f wlo, whi; wlo[0] = wv.x; wlo[1] = wv.y; whi[0] = wv.z; whi[1] = wv.w;
      const v2f hk = bc2(rl_f(h0r, k));
      aA += wlo * hk; aB += whi * hk;
    }
    {
      float4 gv; gv.x = aA[0]; gv.y = aA[1]; gv.z = aB[0]; gv.w = aB[1];
      *(float4*)&gA[w][gbase] = gv;
    }
    __syncthreads();

    {
      float gi = ((gA[0][lane]       + gA[1][lane])       + gA[2][lane])       + gA[3][lane];
      float gf = ((gA[0][64 + lane]  + gA[1][64 + lane])  + gA[2][64 + lane])  + gA[3][64 + lane];
      float gg = ((gA[0][128 + lane] + gA[1][128 + lane]) + gA[2][128 + lane]) + gA[3][128 + lane];
      float go = ((gA[0][192 + lane] + gA[1][192 + lane]) + gA[2][192 + lane]) + gA[3][192 + lane];
      gi += bs0; gf += bs1; gg += bs2; go += bs3;
      c0r = sigm(gf) * c0r + sigm(gi) * tanhf(gg);
      h0r = sigm(go) * tanhf(c0r);
    }

    aA = bc2(0.0f); aB = bc2(0.0f);
#pragma unroll
    for (int kk = 0; kk < 16; kk++) {
      const int k = kh + kk;
      const float4 wv = *(const float4*)&WT10[(k << 8) + gbase];
      v2f wlo, whi; wlo[0] = wv.x; wlo[1] = wv.y; whi[0] = wv.z; whi[1] = wv.w;
      const v2f hk = bc2(rl_f(h0r, k));
      aA += wlo * hk; aB += whi * hk;
    }
#pragma unroll
    for (int kk = 0; kk < 16; kk++) {
      const int k = kh + kk;
      const float4 wv = *(const float4*)&WT11[(k << 8) + gbase];
      v2f wlo, whi; wlo[0] = wv.x; wlo[1] = wv.y; whi[0] = wv.z; whi[1] = wv.w;
      const v2f hk = bc2(rl_f(h1r, k));
      aA += wlo * hk; aB += whi * hk;
    }
    {
      float4 gv; gv.x = aA[0]; gv.y = aA[1]; gv.z = aB[0]; gv.w = aB[1];
      *(float4*)&gB[w][gbase] = gv;
    }
    __syncthreads();

    {
      float gi = ((gB[0][lane]       + gB[1][lane])       + gB[2][lane])       + gB[3][lane];
      float gf = ((gB[0][64 + lane]  + gB[1][64 + lane])  + gB[2][64 + lane])  + gB[3][64 + lane];
      float gg = ((gB[0][128 + lane] + gB[1][128 + lane]) + gB[2][128 + lane]) + gB[3][128 + lane];
      float go = ((gB[0][192 + lane] + gB[1][192 + lane]) + gB[2][192 + lane]) + gB[3][192 + lane];
      gi += bs4; gf += bs5; gg += bs6; go += bs7;
      c1r = sigm(gf) * c1r + sigm(gi) * tanhf(gg);
      h1r = sigm(go) * tanhf(c1r);
      if (w == 0) {
        float pd = h1r * wdfv, pl = h1r * wlocv, ps = h1r * wscv;
#pragma unroll
        for (int off = 32; off > 0; off >>= 1) {
          pd += __shfl_down(pd, off, 64);
          pl += __shfl_down(pl, off, 64);
          ps += __shfl_down(ps, off, 64);
        }
        if (lane == 0) {
          dfo[b * CTX + tt]  = 2.0f + softplusf(pd + bdf);
          loco[b * CTX + tt] = pl + bloc;
          sco[b * CTX + tt]  = softplusf(ps + bsc);
        }
      }
    }
  }
  if (w == 0) {
    h0f[b * 64 + lane] = h0r; c0f[b * 64 + lane] = c0r;
    h1f[b * 64 + lane] = h1r; c1f[b * 64 + lane] = c1r;
  }
}

// ---------------- kernel 3: context sampling (y_ctx) ----------------
__global__ void __launch_bounds__(256) ctx_sample_kernel(
    const float* __restrict__ df, const float* __restrict__ loc, const float* __restrict__ sc,
    const float* __restrict__ tscale, float* __restrict__ yhat,
    u32 kz0, u32 kz1, u32 kg0, u32 kg1)
{
  const int i = blockIdx.x * 256 + threadIdx.x;
  const int r = i / CTX, t = i - r * CTX;
  const int b = r / NSAMP;
  const float dfv = df[b * CTX + t], lv = loc[b * CTX + t], sv = sc[b * CTX + t];
  const float z = normal_from_bits(jx_bits(kz0, kz1, NCTXS, (u32)i));
  u32 gk0, gk1;
  jx_subkey(kg0, kg1, NCTXS, (u32)i, gk0, gk1);
  const float g = jax_gamma_one(gk0, gk1, dfv * 0.5f);
  const float y = (lv + sv * (z * sqrtf(dfv / (2.0f * g)))) * tscale[b];
  yhat[(size_t)r * TM1 + t] = y;
}

// ---------------- kernel 5: persistent decode (MFMA, low-pressure) -----------
// R6: R4/R5 spill-thrashed scratch through HBM (FETCH 3.83 GB, 18:1 read:write
// = loop-invariants reloaded each of 47 steps).  Cut the live set below the
// 128-reg cap instead of raising it: (1) layer-0 bias folded into x-MFMA via
// xh[15]=1.0 + bias in the k=15 weight column (-16 regs); (2) per-gate-column
// (tq) processing: 4 live acc tiles instead of 16 (-48); (3) head weights in
// LDS, prevs as lane-local register, RND load moved into the sampler.
__global__ void __launch_bounds__(512, 2) dec_persist_kernel(
    const float* __restrict__ inp, const float* __restrict__ tscale,
    const f16* __restrict__ WH, const float* __restrict__ emb,
    const float* __restrict__ bih1, const float* __restrict__ bhh1,
    const float* __restrict__ wdf, const float* __restrict__ bdfp,
    const float* __restrict__ wloc, const float* __restrict__ blocp,
    const float* __restrict__ wsc, const float* __restrict__ bscp,
    const float* __restrict__ h0f, const float* __restrict__ c0f,
    const float* __restrict__ h1f, const float* __restrict__ c1f,
    const float* __restrict__ ct, const float* __restrict__ RND,
    float* __restrict__ yhat, u32 kl0, u32 kl1)
{
  const int t    = threadIdx.x;
  const int lane = t & 63;
  const int w    = t >> 6;        // wave 0..7
  const int r0   = w * RPW;       // wave's first local row
  const int c16  = lane & 15;     // gate col within tile / A row select
  const int kg   = lane >> 4;     // k-group / D row-group

  __shared__ __align__(16) f16   wgt[WH_TOT];        // 104 KB B-fragment weights
  __shared__ __align__(16) f16   h0h[DROWS * HSTR];  // 18 KB
  __shared__ __align__(16) f16   h1h[DROWS * HSTR];  // 18 KB
  __shared__ __align__(16) f16   xh[DROWS][32];      // 8 KB (15 = 1.0, 16..31 = 0)
  __shared__ __align__(16) f16   hist[DROWS][32];    // 8 KB lag ring
  __shared__ __align__(16) f16   fst[3][NSTEP][2];   // X ch2 / ch1 stash
  __shared__ __align__(16) float hw[3][64];          // head weights (df/loc/sc)
  __shared__ float tsr[DROWS];
  __shared__ float dfL[DROWS], locL[DROWS], scL[DROWS];
  __shared__ unsigned char rsel[DROWS];

  const int base = blockIdx.x * DROWS;
  const int bblo = base / NSAMP;

  // ---- stage all weights once: 13 x (8 waves x 64 lanes x 16B) ----
#pragma unroll
  for (int i = 0; i < 13; i++) {
    const int off = (i * 8 + w) * 512;   // halves
    __builtin_amdgcn_global_load_lds(
        (const __attribute__((address_space(1))) void*)(WH + off + lane * 8),
        (__attribute__((address_space(3))) void*)(wgt + off), 16, 0, 0);
  }

  // ---- per-lane constants: layer-1 bias (16 regs) + c-state (32 regs) ----
  float b1[4][4];
#pragma unroll
  for (int gq = 0; gq < 4; gq++)
#pragma unroll
    for (int tq = 0; tq < 4; tq++) {
      const int g = gq * 64 + tq * 16 + c16;
      b1[gq][tq] = bih1[g] + bhh1[g];
    }
  const float bdf = bdfp[0], bloc = blocp[0], bsc = bscp[0];
  const float embv = emb[0];

  float c0reg[4][4], c1reg[4][4];
#pragma unroll
  for (int rr = 0; rr < 4; rr++) {
    const int row = r0 + kg * 4 + rr;
    const int bb = (base + row) / NSAMP;
#pragma unroll
    for (int tq = 0; tq < 4; tq++) {
      c0reg[rr][tq] = c0f[bb * 64 + tq * 16 + c16];
      c1reg[rr][tq] = c1f[bb * 64 + tq * 16 + c16];
    }
  }

  // ---- h state into LDS (stride HSTR) ----
  for (int idx = t; idx < DROWS * 64; idx += 512) {
    const int row = idx >> 6, hid = idx & 63;
    const int bb = (base + row) / NSAMP;
    h0h[row * HSTR + hid] = (f16)h0f[bb * 64 + hid];
    h1h[row * HSTR + hid] = (f16)h1f[bb * 64 + hid];
  }

  for (int idx = t; idx < DROWS * 28; idx += 512) {
    const int i = idx / 28, k = idx - i * 28;
    const int bb = (base + i) / NSAMP;
    hist[i][31 - k] = (f16)ct[bb * CTX + 335 - k];
  }
  // feature stash (X ch2 @f=12, X ch1 @f=14); block spans <=3 batch indices
  for (int idx = t; idx < 3 * NSTEP * 2; idx += 512) {
    const int sel = idx / (NSTEP * 2), rem = idx - sel * (NSTEP * 2);
    const int s = rem >> 1, f = rem & 1;
    const int bb = min(bblo + sel, NB - 1);
    fst[sel][s][f] = (f16)inp[((size_t)bb * TM1 + CTX + s) * NIN + (f ? 14 : 12)];
  }
  if (t < 64)        hw[0][t]       = wdf[t];
  else if (t < 128)  hw[1][t - 64]  = wloc[t - 64];
  else if (t < 192)  hw[2][t - 128] = wsc[t - 128];
  if (t < DROWS) {
    const int rg = base + t;
    tsr[t] = tscale[rg / NSAMP];
    xh[t][15] = (f16)1.0f;                               // bias lane (W[k=15]=b0)
    for (int j = 16; j < 32; j++) xh[t][j] = (f16)0.0f;  // hard-zero K pad
    rsel[t] = (unsigned char)((rg / NSAMP) - bblo);
  }
  float prevreg = 0.f;
  if (lane < RPW) prevreg = yhat[(size_t)(base + r0 + lane) * TM1 + 335];
  __syncthreads();   // covers weight staging (vmcnt drain) + all init writes

  const int arow = r0 + c16;         // A-fragment row for this lane

#define BFR(off) (*(const half8*)&wgt[(off) + lane * 8])

  for (int s = 0; s < NSTEP; s++) {
    // ---- parallel x-build (slots 0..14; 15 stays 1.0, 16..31 zero) ----
    if (lane < RPW) {
      const int row = r0 + lane;
      const float nv = prevreg / tsr[row];
      const f16 nh = (f16)nv;
      xh[row][0] = nh;
      hist[row][s & 31] = nh;
    }
    {
      const int rq = lane >> 2, q = lane & 3;
      const int row = r0 + rq;
#pragma unroll
      for (int p = 0; p < 4; p++) {
        const int sl = 1 + q + p * 4;          // 1..16
        if (sl <= 10) {
          xh[row][sl] = hist[row][(s - c_LAGS[sl - 1]) & 31];
        } else if (sl == 11) {
          xh[row][sl] = (f16)embv;
        } else if (sl == 12) {
          xh[row][sl] = fst[rsel[row]][s][0];
        } else if (sl == 13) {
          xh[row][sl] = (f16)logf(tsr[row]);
        } else if (sl == 14) {
          xh[row][sl] = fst[rsel[row]][s][1];
        }
      }
    }

    // ---- layer 0: A-frags, then per-gate-column (tq) MFMA + cell ----
    const half8 ax  = *(const half8*)&xh[arow][kg * 8];
    const half8 a00 = *(const half8*)&h0h[arow * HSTR + kg * 8];
    const half8 a01 = *(const half8*)&h0h[arow * HSTR + 32 + kg * 8];
#pragma unroll
    for (int tq = 0; tq < 4; tq++) {
      floatx4 ai = {0.f, 0.f, 0.f, 0.f};
      floatx4 af = {0.f, 0.f, 0.f, 0.f};
      floatx4 ag = {0.f, 0.f, 0.f, 0.f};
      floatx4 ao = {0.f, 0.f, 0.f, 0.f};
      ai = __builtin_amdgcn_mfma_f32_16x16x32_f16(ax, BFR(WH_X + (tq)      * 256), ai, 0, 0, 0);
      af = __builtin_amdgcn_mfma_f32_16x16x32_f16(ax, BFR(WH_X + (4 + tq)  * 256), af, 0, 0, 0);
      ag = __builtin_amdgcn_mfma_f32_16x16x32_f16(ax, BFR(WH_X + (8 + tq)  * 256), ag, 0, 0, 0);
      ao = __builtin_amdgcn_mfma_f32_16x16x32_f16(ax, BFR(WH_X + (12 + tq) * 256), ao, 0, 0, 0);
      ai = __builtin_amdgcn_mfma_f32_16x16x32_f16(a00, BFR(WH_00 + ((tq) * 2 + 0)      * 512), ai, 0, 0, 0);
      ai = __builtin_amdgcn_mfma_f32_16x16x32_f16(a01, BFR(WH_00 + ((tq) * 2 + 1)      * 512), ai, 0, 0, 0);
      af = __builtin_amdgcn_mfma_f32_16x16x32_f16(a00, BFR(WH_00 + ((4 + tq) * 2 + 0)  * 512), af, 0, 0, 0);
      af = __builtin_amdgcn_mfma_f32_16x16x32_f16(a01, BFR(WH_00 + ((4 + tq) * 2 + 1)  * 512), af, 0, 0, 0);
      ag = __builtin_amdgcn_mfma_f32_16x16x32_f16(a00, BFR(WH_00 + ((8 + tq) * 2 + 0)  * 512), ag, 0, 0, 0);
      ag = __builtin_amdgcn_mfma_f32_16x16x32_f16(a01, BFR(WH_00 + ((8 + tq) * 2 + 1)  * 512), ag, 0, 0, 0);
      ao = __builtin_amdgcn_mfma_f32_16x16x32_f16(a00, BFR(WH_00 + ((12 + tq) * 2 + 0) * 512), ao, 0, 0, 0);
      ao = __builtin_amdgcn_mfma_f32_16x16x32_f16(a01, BFR(WH_00 + ((12 + tq) * 2 + 1) * 512), ao, 0, 0, 0);
#pragma unroll
      for (int rr = 0; rr < 4; rr++) {
        const float gi = ai[rr], gf = af[rr], gg = ag[rr], go = ao[rr];
        float cc = c0reg[rr][tq];
        cc = sigm(gf) * cc + sigm(gi) * tanhf(gg);
        c0reg[rr][tq] = cc;
        h0h[(r0 + kg * 4 + rr) * HSTR + tq * 16 + c16] = (f16)(sigm(go) * tanhf(cc));
      }
    }

    // ---- layer 1: A-frags (h0_new complete), per-tq MFMA + cell + head ----
    const half8 a10a = *(const half8*)&h0h[arow * HSTR + kg * 8];
    const half8 a10b = *(const half8*)&h0h[arow * HSTR + 32 + kg * 8];
    const half8 a11a = *(const half8*)&h1h[arow * HSTR + kg * 8];
    const half8 a11b = *(const half8*)&h1h[arow * HSTR + 32 + kg * 8];
    float pd[4] = {0.f, 0.f, 0.f, 0.f};
    float pl[4] = {0.f, 0.f, 0.f, 0.f};
    float ps[4] = {0.f, 0.f, 0.f, 0.f};
#pragma unroll
    for (int tq = 0; tq < 4; tq++) {
      const float bi = b1[0][tq], bf = b1[1][tq], bg = b1[2][tq], bo = b1[3][tq];
      floatx4 ai = {bi, bi, bi, bi};
      floatx4 af = {bf, bf, bf, bf};
      floatx4 ag = {bg, bg, bg, bg};
      floatx4 ao = {bo, bo, bo, bo};
      ai = __builtin_amdgcn_mfma_f32_16x16x32_f16(a10a, BFR(WH_10 + ((tq) * 2 + 0)      * 512), ai, 0, 0, 0);
      ai = __builtin_amdgcn_mfma_f32_16x16x32_f16(a10b, BFR(WH_10 + ((tq) * 2 + 1)      * 512), ai, 0, 0, 0);
      ai = __builtin_amdgcn_mfma_f32_16x16x32_f16(a11a, BFR(WH_11 + ((tq) * 2 + 0)      * 512), ai, 0, 0, 0);
      ai = __builtin_amdgcn_mfma_f32_16x16x32_f16(a11b, BFR(WH_11 + ((tq) * 2 + 1)      * 512), ai, 0, 0, 0);
      af = __builtin_amdgcn_mfma_f32_16x16x32_f16(a10a, BFR(WH_10 + ((4 + tq) * 2 + 0)  * 512), af, 0, 0, 0);
      af = __builtin_amdgcn_mfma_f32_16x16x32_f16(a10b, BFR(WH_10 + ((4 + tq) * 2 + 1)  * 512), af, 0, 0, 0);
      af = __builtin_amdgcn_mfma_f32_16x16x32_f16(a11a, BFR(WH_11 + ((4 + tq) * 2 + 0)  * 512), af, 0, 0, 0);
      af = __builtin_amdgcn_mfma_f32_16x16x32_f16(a11b, BFR(WH_11 + ((4 + tq) * 2 + 1)  * 512), af, 0, 0, 0);
      ag = __builtin_amdgcn_mfma_f32_16x16x32_f16(a10a, BFR(WH_10 + ((8 + tq) * 2 + 0)  * 512), ag, 0, 0, 0);
      ag = __builtin_amdgcn_mfma_f32_16x16x32_f16(a10b, BFR(WH_10 + ((8 + tq) * 2 + 1)  * 512), ag, 0, 0, 0);
      ag = __builtin_amdgcn_mfma_f32_16x16x32_f16(a11a, BFR(WH_11 + ((8 + tq) * 2 + 0)  * 512), ag, 0, 0, 0);
      ag = __builtin_amdgcn_mfma_f32_16x16x32_f16(a11b, BFR(WH_11 + ((8 + tq) * 2 + 1)  * 512), ag, 0, 0, 0);
      ao = __builtin_amdgcn_mfma_f32_16x16x32_f16(a10a, BFR(WH_10 + ((12 + tq) * 2 + 0) * 512), ao, 0, 0, 0);
      ao = __builtin_amdgcn_mfma_f32_16x16x32_f16(a10b, BFR(WH_10 + ((12 + tq) * 2 + 1) * 512), ao, 0, 0, 0);
      ao = __builtin_amdgcn_mfma_f32_16x16x32_f16(a11a, BFR(WH_11 + ((12 + tq) * 2 + 0) * 512), ao, 0, 0, 0);
      ao = __builtin_amdgcn_mfma_f32_16x16x32_f16(a11b, BFR(WH_11 + ((12 + tq) * 2 + 1) * 512), ao, 0, 0, 0);
      const float hwd = hw[0][tq * 16 + c16];
      const float hwl = hw[1][tq * 16 + c16];
      const float hws = hw[2][tq * 16 + c16];
#pragma unroll
      for (int rr = 0; rr < 4; rr++) {
        const float gi = ai[rr], gf = af[rr], gg = ag[rr], go = ao[rr];
        float cc = c1reg[rr][tq];
        cc = sigm(gf) * cc + sigm(gi) * tanhf(gg);
        c1reg[rr][tq] = cc;
        const float h1v = sigm(go) * tanhf(cc);
        h1h[(r0 + kg * 4 + rr) * HSTR + tq * 16 + c16] = (f16)h1v;
        pd[rr] += h1v * hwd;
        pl[rr] += h1v * hwl;
        ps[rr] += h1v * hws;
      }
    }
    // reduce across the 16 cols (lanes share kg within width-16 groups)
#pragma unroll
    for (int rr = 0; rr < 4; rr++) {
#pragma unroll
      for (int off = 8; off >= 1; off >>= 1) {
        pd[rr] += __shfl_xor(pd[rr], off, 16);
        pl[rr] += __shfl_xor(pl[rr], off, 16);
        ps[rr] += __shfl_xor(ps[rr], off, 16);
      }
    }
    if (c16 == 0) {
#pragma unroll
      for (int rr = 0; rr < 4; rr++) {
        const int row = r0 + kg * 4 + rr;
        dfL[row]  = 2.0f + softplusf(pd[rr] + bdf);
        locL[row] = pl[rr] + bloc;
        scL[row]  = softplusf(ps[rr] + bsc);
      }
    }

    // ---- sample (one lane per row, 16 rows in parallel) ----
    if (lane < RPW) {
      const int row = r0 + lane, rg = base + row;
      const float4 R = *(const float4*)(RND + ((size_t)s * RTOT + rg) * 4);
      const float dfv = dfL[row], lv = locL[row], scv = scL[row];
      const float z = R.x;
      const float alpha = dfv * 0.5f;
      float gam;
      {
#pragma clang fp contract(off)
        const float d = alpha - 0.33333334f;
        const float c = 0.33333334f / sqrtf(d);
        float x = R.y;
        float v = 1.0f + x * c;
        bool ok = true;
        if (v <= 0.0f) { x = R.z; v = 1.0f + x * c; ok = (v > 0.0f); }
        const float X = x * x;
        const float V = (v * v) * v;
        const float U = R.w;
        bool accept = false;
        if (ok) {
          if (!(U >= 1.0f - 0.0331f * (X * X))) accept = true;
          else if (!(logf(U) >= 0.5f * X + d * ((1.0f - V) + logf(V)))) accept = true;
        }
        if (accept) {
          gam = d * V;
        } else {
          u32 ks0, ks1, skg0, skg1, gk0, gk1;
          tf2x32(kl0, kl1, 0u, (u32)s, ks0, ks1);
          tf2x32(ks0, ks1, 0u, 1u, skg0, skg1);
          jx_subkey(skg0, skg1, RTOT, (u32)rg, gk0, gk1);
          gam = jax_gamma_one(gk0, gk1, alpha);
        }
      }
      const float y = (lv + scv * (z * sqrtf(dfv / (2.0f * gam)))) * tsr[row];
      yhat[(size_t)rg * TM1 + CTX + s] = y;
      prevreg = y;
    }
  }
#undef BFR
}

// ---------------- kernel 6: median over 100 samples per (b,t) ----------------
__global__ void __launch_bounds__(256) median_kernel(
    const float* __restrict__ yhat, float* __restrict__ out)
{
  __shared__ float vals[4][100];
  const int wave = threadIdx.x >> 6, lane = threadIdx.x & 63;
  const int cell = blockIdx.x * 4 + wave;
  const int b = cell / TM1, t = cell - b * TM1;
  const float* basep = yhat + (size_t)b * NSAMP * TM1 + t;
  const float v1 = basep[(size_t)lane * TM1];
  vals[wave][lane] = v1;
  float v2 = 0.f;
  if (lane < 36) { v2 = basep[(size_t)(64 + lane) * TM1]; vals[wave][64 + lane] = v2; }
  __syncthreads();
  int cl1 = 0, ce1 = 0, cl2 = 0, ce2 = 0;
  for (int jj = 0; jj < 100; jj++) {
    const float w = vals[wave][jj];
    cl1 += (w < v1); ce1 += (w == v1);
    cl2 += (w < v2); ce2 += (w == v2);
  }
  if (cl1 <= 49 && 49 < cl1 + ce1) out[cell] = v1;
  if (lane < 36 && cl2 <= 49 && 49 < cl2 + ce2) out[cell] = v2;
}

// ---------------- launch ----------------
extern "C" void kernel_launch(void* const* d_in, const int* in_sizes, int n_in,
                              void* d_out, int out_size, void* d_ws, size_t ws_size,
                              hipStream_t stream) {
  (void)in_sizes; (void)n_in; (void)out_size; (void)ws_size;
  const float* X     = (const float*)d_in[0];
  const float* Wih0  = (const float*)d_in[2];
  const float* Whh0  = (const float*)d_in[3];
  const float* bih0  = (const float*)d_in[4];
  const float* bhh0  = (const float*)d_in[5];
  const float* Wih1  = (const float*)d_in[6];
  const float* Whh1  = (const float*)d_in[7];
  const float* bih1  = (const float*)d_in[8];
  const float* bhh1  = (const float*)d_in[9];
  const float* wdf   = (const float*)d_in[10];
  const float* bdf   = (const float*)d_in[11];
  const float* wloc  = (const float*)d_in[12];
  const float* bloc  = (const float*)d_in[13];
  const float* wsc   = (const float*)d_in[14];
  const float* bsc   = (const float*)d_in[15];
  const float* emb   = (const float*)d_in[16];

  float* wsf = (float*)d_ws;
  float* inp  = wsf + OFF_INP;
  float* ct   = wsf + OFF_CT;
  float* ts   = wsf + OFF_TS;
  float* lts  = wsf + OFF_LTS;
  float* dfp  = wsf + OFF_DF;
  float* locp = wsf + OFF_LOC;
  float* scp  = wsf + OFF_SC;
  float* h0f  = wsf + OFF_H0F;
  float* c0f  = wsf + OFF_C0F;
  float* h1f  = wsf + OFF_H1F;
  float* c1f  = wsf + OFF_C1F;
  float* yhat = wsf + OFF_YH;
  float* wtx  = wsf + OFF_WTX;
  float* wt00 = wsf + OFF_WT00;
  float* wt10 = wsf + OFF_WT10;
  float* wt11 = wsf + OFF_WT11;
  f16*   wh   = (f16*)(wsf + OFF_WH);
  float* rnd  = wsf + OFF_RND;

  const u32 key0 = 0u, key1 = 42u;
  u32 kc0, kc1, kl0, kl1;
  jx_subkey(key0, key1, 2u, 0u, kc0, kc1);
  jx_subkey(key0, key1, 2u, 1u, kl0, kl1);
  u32 kz0, kz1, kg0, kg1;
  jx_subkey(kc0, kc1, 2u, 0u, kz0, kz1);
  jx_subkey(kc0, kc1, 2u, 1u, kg0, kg1);

  wtrans_kernel<<<208, 256, 0, stream>>>(Wih0, Whh0, Wih1, Whh1, wtx, wt00, wt10, wt11);
  wh_kernel<<<208, 256, 0, stream>>>(Wih0, Whh0, Wih1, Whh1, bih0, bhh0, wh);
  rnd_dec_kernel<<<(NSTEP * RTOT) / 256, 256, 0, stream>>>(rnd, kl0, kl1);
  prep_kernel<<<NB, 256, 0, stream>>>(X, emb, inp, ct, ts, lts);
  ctx_lstm_kernel<<<NB, 256, 0, stream>>>(inp, wtx, wt00, wt10, wt11,
                                          bih0, bhh0, bih1, bhh1,
                                          wdf, bdf, wloc, bloc, wsc, bsc,
                                          dfp, locp, scp, h0f, c0f, h1f, c1f);
  ctx_sample_kernel<<<NCTXS / 256, 256, 0, stream>>>(dfp, locp, scp, ts, yhat, kz0, kz1, kg0, kg1);
  dec_persist_kernel<<<DBLOCKS, 512, 0, stream>>>(inp, ts, wh, emb,
                                                  bih1, bhh1,
                                                  wdf, bdf, wloc, bloc, wsc, bsc,
                                                  h0f, c0f, h1f, c1f, ct, rnd, yhat, kl0, kl1);
  median_kernel<<<(NB * TM1) / 4, 256, 0, stream>>>(yhat, (float*)d_out);
}

// Round 8
// 2490.156 us; speedup vs baseline: 1.4508x; 1.1852x over previous
//
#include <hip/hip_runtime.h>
#include <stdint.h>
#include <stddef.h>

typedef uint32_t u32;
typedef float v2f __attribute__((ext_vector_type(2)));
typedef _Float16 f16;
typedef f16 half8 __attribute__((ext_vector_type(8)));
typedef float floatx4 __attribute__((ext_vector_type(4)));

// ---------------- problem constants (fixed by reference file) ----------------
#define NB    256      // batch B
#define LFULL 412      // L
#define NCH   3        // C
#define CTX   336      // context_length
#define NSAMP 100      // n_samples
#define TM1   383      // T-1 (T = L - MAX_LAG = 384)
#define HID   64
#define NIN   15
#define RTOT  25600    // NB*NSAMP
#define NCTXS 8601600u // RTOT*CTX
#define NSTEP 47       // H-1

#define DROWS   128    // rows per persistent decode block (16 per wave, 8 waves)
#define RPW     16     // rows per wave
#define DBLOCKS (RTOT / DROWS)  // 200 -> 1 dispatch round on 256 CUs

#define HSTR    72     // h-array LDS stride in halves (144 B, 16B-aligned, bank-spread)

#define JAX_PARTITIONABLE 1

__device__ const int c_LAGS[10] = {1,2,3,4,5,6,7,14,21,28};

__device__ inline v2f bc2(float x) { v2f r; r[0] = x; r[1] = x; return r; }

// ---------------- threefry2x32 (matches jax._src.prng) ----------------
__host__ __device__ inline void tf2x32(u32 k0, u32 k1, u32 x0, u32 x1, u32& o0, u32& o1) {
  const u32 ks2 = k0 ^ k1 ^ 0x1BD11BDAu;
#define TFR(r) { x0 += x1; x1 = (x1 << (r)) | (x1 >> (32 - (r))); x1 ^= x0; }
  x0 += k0; x1 += k1;
  TFR(13) TFR(15) TFR(26) TFR(6)
  x0 += k1; x1 += ks2 + 1u;
  TFR(17) TFR(29) TFR(16) TFR(24)
  x0 += ks2; x1 += k0 + 2u;
  TFR(13) TFR(15) TFR(26) TFR(6)
  x0 += k0; x1 += k1 + 3u;
  TFR(17) TFR(29) TFR(16) TFR(24)
  x0 += k1; x1 += ks2 + 4u;
  TFR(13) TFR(15) TFR(26) TFR(6)
  x0 += ks2; x1 += k0 + 5u;
#undef TFR
  o0 = x0; o1 = x1;
}

__host__ __device__ inline u32 split_word_legacy(u32 k0, u32 k1, u32 n, u32 j) {
  u32 o0, o1;
  if (j < n) { tf2x32(k0, k1, j, n + j, o0, o1); return o0; }
  tf2x32(k0, k1, j - n, j, o0, o1); return o1;
}

__host__ __device__ inline void jx_subkey(u32 k0, u32 k1, u32 n, u32 i, u32& s0, u32& s1) {
#if JAX_PARTITIONABLE
  (void)n; tf2x32(k0, k1, 0u, i, s0, s1);
#else
  s0 = split_word_legacy(k0, k1, n, 2u * i);
  s1 = split_word_legacy(k0, k1, n, 2u * i + 1u);
#endif
}

__device__ inline u32 jx_bits(u32 k0, u32 k1, u32 n, u32 i) {
#if JAX_PARTITIONABLE
  (void)n; u32 o0, o1; tf2x32(k0, k1, 0u, i, o0, o1); return o0 ^ o1;
#else
  u32 o0, o1;
  if (n == 1u) { tf2x32(k0, k1, 0u, 0u, o0, o1); return o0; }
  const u32 h = n >> 1;
  if (i < h) { tf2x32(k0, k1, i, h + i, o0, o1); return o0; }
  tf2x32(k0, k1, i - h, i, o0, o1); return o1;
#endif
}

// ---------------- JAX-exact float transforms ----------------
__device__ inline float jax_erfinv(float x) {
#pragma clang fp contract(off)
  float w = -log1pf(-x * x);
  float p;
  if (w < 5.0f) {
    w = w - 2.5f;
    p = 2.81022636e-08f;
    p = 3.43273939e-07f + p * w;
    p = -3.5233877e-06f + p * w;
    p = -4.39150654e-06f + p * w;
    p = 0.00021858087f + p * w;
    p = -0.00125372503f + p * w;
    p = -0.00417768164f + p * w;
    p = 0.246640727f + p * w;
    p = 1.50140941f + p * w;
  } else {
    w = sqrtf(w) - 3.0f;
    p = -0.000200214257f;
    p = 0.000100950558f + p * w;
    p = 0.00134934322f + p * w;
    p = -0.00367342844f + p * w;
    p = 0.00573950773f + p * w;
    p = -0.0076224613f + p * w;
    p = 0.00943887047f + p * w;
    p = 1.00167406f + p * w;
    p = 2.83297682f + p * w;
  }
  return p * x;
}

__device__ inline float u01_from_bits(u32 bits) {
  return __uint_as_float((bits >> 9) | 0x3f800000u) - 1.0f;
}

__device__ inline float normal_from_bits(u32 bits) {
#pragma clang fp contract(off)
  const float lo = -0.99999994f;
  const float u = u01_from_bits(bits);
  float r = u * 2.0f + lo;
  r = fmaxf(lo, r);
  return 1.41421356f * jax_erfinv(r);
}

__device__ float jax_gamma_one(u32 k0, u32 k1, float alpha) {
#pragma clang fp contract(off)
  const bool boost_mask = (alpha >= 1.0f);
  const float alpha_orig = alpha;
  const float a = boost_mask ? alpha : (alpha + 1.0f);
  const float d = a - 0.33333334f;
  const float c = 0.33333334f / sqrtf(d);
  u32 K0, K1, S0, S1;
  jx_subkey(k0, k1, 2u, 0u, K0, K1);
  jx_subkey(k0, k1, 2u, 1u, S0, S1);
  float u_boost = 1.0f;
  if (!boost_mask) u_boost = u01_from_bits(jx_bits(S0, S1, 1u, 0u));
  float X = 0.0f, V = 1.0f, U = 2.0f;
  while (true) {
    if (!(U >= 1.0f - 0.0331f * (X * X))) break;
    if (!(logf(U) >= 0.5f * X + d * ((1.0f - V) + logf(V)))) break;
    u32 nk0, nk1, xk0, xk1, uk0, uk1;
    jx_subkey(K0, K1, 3u, 0u, nk0, nk1);
    jx_subkey(K0, K1, 3u, 1u, xk0, xk1);
    jx_subkey(K0, K1, 3u, 2u, uk0, uk1);
    K0 = nk0; K1 = nk1;
    float x, v;
    u32 c0 = xk0, c1 = xk1;
    do {
      u32 t0, t1, s0, s1;
      jx_subkey(c0, c1, 2u, 0u, t0, t1);
      jx_subkey(c0, c1, 2u, 1u, s0, s1);
      c0 = t0; c1 = t1;
      x = normal_from_bits(jx_bits(s0, s1, 1u, 0u));
      v = 1.0f + x * c;
    } while (v <= 0.0f);
    X = x * x;
    V = (v * v) * v;
    U = u01_from_bits(jx_bits(uk0, uk1, 1u, 0u));
  }
  const float sample = d * V;
  const float boost = boost_mask ? 1.0f : powf(u_boost, 1.0f / alpha_orig);
  return sample * boost;
}

__device__ inline float sigm(float x) { return 1.0f / (1.0f + expf(-x)); }
__device__ inline float softplusf(float x) { return fmaxf(x, 0.0f) + log1pf(expf(-fabsf(x))); }

// cross-lane broadcast on the VALU pipe (not DS): v_readlane -> SGPR (ctx kernel)
__device__ inline float rl_f(float v, int l) {
  return __int_as_float(__builtin_amdgcn_readlane(__float_as_int(v), l));
}

// ---------------- workspace layout (floats) ----------------
enum : size_t {
  OFF_INP  = 0,
  OFF_CT   = OFF_INP + (size_t)NB * TM1 * NIN,
  OFF_TS   = OFF_CT + (size_t)NB * CTX,
  OFF_LTS  = OFF_TS + NB,
  OFF_DF   = OFF_LTS + NB,
  OFF_LOC  = OFF_DF + (size_t)NB * CTX,
  OFF_SC   = OFF_LOC + (size_t)NB * CTX,
  OFF_H0F  = OFF_SC + (size_t)NB * CTX,
  OFF_C0F  = OFF_H0F + (size_t)NB * HID,
  OFF_H1F  = OFF_C0F + (size_t)NB * HID,
  OFF_C1F  = OFF_H1F + (size_t)NB * HID,
  OFF_YH   = OFF_C1F + (size_t)NB * HID,
  OFF_WTX  = OFF_YH + (size_t)RTOT * TM1,     // Wih0^T padded [16][256] (ctx kernel)
  OFF_WT00 = OFF_WTX + 4096,                  // Whh0^T [64][256]
  OFF_WT10 = OFF_WT00 + 16384,                // Wih1^T [64][256]
  OFF_WT11 = OFF_WT10 + 16384,                // Whh1^T [64][256]
  OFF_WH   = OFF_WT11 + 16384,                // fp16 MFMA-fragment weights, 53248 halves
  OFF_RND  = OFF_WH + 26624,                  // decode randoms [NSTEP][RTOT][4]
  WS_FLOATS = OFF_RND + (size_t)NSTEP * RTOT * 4
};

// fp16 weight blob segment offsets (in halves)
#define WH_X   0        // layer0 x-part: 16 nt x (32 lanes x 8 halves); k=15 = bias0 (x[15]=1)
#define WH_00  4096     // layer0 h-part: 16 nt x 2 kchunk x (64 x 8)   16x16x32 B-frags
#define WH_10  20480    // layer1 h0-part
#define WH_11  36864    // layer1 h1-part
#define WH_TOT 53248

// ---------------- kernel 0a: transpose weights (fp32, ctx kernel) -----------
__global__ void __launch_bounds__(256) wtrans_kernel(
    const float* __restrict__ Wih0, const float* __restrict__ Whh0,
    const float* __restrict__ Wih1, const float* __restrict__ Whh1,
    float* __restrict__ WTx, float* __restrict__ WT00,
    float* __restrict__ WT10, float* __restrict__ WT11)
{
  const int i = blockIdx.x * 256 + threadIdx.x;   // < 53248
  if (i < 4096) {
    const int k = i >> 8, g = i & 255;
    WTx[i] = (k < 15) ? Wih0[g * 15 + k] : 0.0f;
  } else if (i < 4096 + 16384) {
    const int j = i - 4096, k = j >> 8, g = j & 255;
    WT00[j] = Whh0[g * 64 + k];
  } else if (i < 4096 + 32768) {
    const int j = i - 4096 - 16384, k = j >> 8, g = j & 255;
    WT10[j] = Wih1[g * 64 + k];
  } else {
    const int j = i - 4096 - 32768, k = j >> 8, g = j & 255;
    WT11[j] = Whh1[g * 64 + k];
  }
}

// ---------------- kernel 0a2: fp16 MFMA B-fragment weights for decode --------
// All fragments use the verified shape 16x16x32 (m89/m97 family):
//  h-part:  lane l holds B[k=kc*32+(l>>4)*8+e][n=nt*16+(l&15)], e=0..7 (16B/lane)
//  x-part:  K=32 zero-padded; lanes 0..31 carry k=0..15; k==15 slot = layer-0
//           bias (bih0+bhh0), paired with xh[row][15]=1.0.
__global__ void __launch_bounds__(256) wh_kernel(
    const float* __restrict__ Wih0, const float* __restrict__ Whh0,
    const float* __restrict__ Wih1, const float* __restrict__ Whh1,
    const float* __restrict__ bih0, const float* __restrict__ bhh0,
    f16* __restrict__ WH)
{
  const int j = blockIdx.x * 256 + threadIdx.x;   // < 53248
  if (j < WH_00) {
    const int nt = j >> 8, rem = j & 255;
    const int l = rem >> 3, e = rem & 7;          // l = 0..31
    const int g = nt * 16 + (l & 15);
    const int k = (l >> 4) * 8 + e;               // k = 0..15
    WH[j] = (f16)((k < 15) ? Wih0[g * 15 + k] : (bih0[g] + bhh0[g]));
  } else {
    const float* W; int q;
    if (j < WH_10)      { W = Whh0; q = j - WH_00; }
    else if (j < WH_11) { W = Wih1; q = j - WH_10; }
    else                { W = Whh1; q = j - WH_11; }
    const int blk = q >> 9, rem = q & 511;   // blk = nt*2 + kc
    const int l = rem >> 3, e = rem & 7;
    const int nt = blk >> 1, kc = blk & 1;
    const int g = nt * 16 + (l & 15);
    const int k = kc * 32 + (l >> 4) * 8 + e;
    WH[j] = (f16)W[g * 64 + k];
  }
}

// ---------------- kernel 0b: precompute decode randoms -----------------------
__global__ void __launch_bounds__(256) rnd_dec_kernel(
    float* __restrict__ RND, u32 kl0, u32 kl1)
{
  const int i = blockIdx.x * 256 + threadIdx.x;   // < NSTEP*RTOT = 1203200
  const int s = i / RTOT, rg = i - s * RTOT;
  u32 ks0, ks1, skz0, skz1, skg0, skg1;
  tf2x32(kl0, kl1, 0u, (u32)s, ks0, ks1);
  tf2x32(ks0, ks1, 0u, 0u, skz0, skz1);
  tf2x32(ks0, ks1, 0u, 1u, skg0, skg1);
  const float z = normal_from_bits(jx_bits(skz0, skz1, RTOT, (u32)rg));
  u32 gk0, gk1;
  jx_subkey(skg0, skg1, RTOT, (u32)rg, gk0, gk1);
  u32 K0, K1, S0, S1;
  jx_subkey(gk0, gk1, 2u, 0u, K0, K1);
  jx_subkey(gk0, gk1, 2u, 1u, S0, S1);   // boost key, unused (alpha >= 1)
  u32 nk0, nk1, xk0, xk1, uk0, uk1;
  jx_subkey(K0, K1, 3u, 0u, nk0, nk1);
  jx_subkey(K0, K1, 3u, 1u, xk0, xk1);
  jx_subkey(K0, K1, 3u, 2u, uk0, uk1);
  u32 c0 = xk0, c1 = xk1, t0, t1, s0, s1;
  jx_subkey(c0, c1, 2u, 0u, t0, t1);
  jx_subkey(c0, c1, 2u, 1u, s0, s1);
  const float x1 = normal_from_bits(jx_bits(s0, s1, 1u, 0u));
  c0 = t0; c1 = t1;
  jx_subkey(c0, c1, 2u, 0u, t0, t1);
  jx_subkey(c0, c1, 2u, 1u, s0, s1);
  const float x2 = normal_from_bits(jx_bits(s0, s1, 1u, 0u));
  const float U1 = u01_from_bits(jx_bits(uk0, uk1, 1u, 0u));
  float* R = RND + (size_t)i * 4;
  R[0] = z; R[1] = x1; R[2] = x2; R[3] = U1;
}

// ---------------- kernel 1: tscale + feature build ----------------
__global__ void __launch_bounds__(256) prep_kernel(
    const float* __restrict__ X, const float* __restrict__ emb,
    float* __restrict__ inp, float* __restrict__ ct,
    float* __restrict__ tscale, float* __restrict__ ltscale)
{
  const int b = blockIdx.x, t = threadIdx.x;
  __shared__ float red[256];
  __shared__ float ts_sh;
  const float* Xb = X + (size_t)b * LFULL * NCH;
  float p = fabsf(Xb[(28 + t) * NCH]);
  if (t < 80) p += fabsf(Xb[(28 + 256 + t) * NCH]);
  red[t] = p;
  for (int st = 128; st > 0; st >>= 1) { __syncthreads(); if (t < st) red[t] += red[t + st]; }
  __syncthreads();
  if (t == 0) {
    float ts = red[0] / 336.0f;
    ts = fmaxf(ts, 1e-10f);
    tscale[b] = ts; ltscale[b] = logf(ts); ts_sh = ts;
  }
  __syncthreads();
  const float ts = ts_sh;
  const float lts = logf(ts);
  const float ev = emb[0];
  for (int idx = t; idx < TM1 * NIN; idx += 256) {
    const int tt = idx / NIN, f = idx - tt * NIN;
    float val;
    if (f == 0)       val = (tt < CTX) ? Xb[(28 + tt) * NCH] / ts : 0.0f;
    else if (f <= 10) val = (tt < CTX) ? Xb[(28 + tt - c_LAGS[f - 1]) * NCH] / ts : 0.0f;
    else if (f == 11) val = ev;
    else if (f == 12) val = Xb[(28 + tt) * NCH + 2];
    else if (f == 13) val = lts;
    else              val = Xb[(28 + tt) * NCH + 1];
    inp[(size_t)(b * TM1 + tt) * NIN + f] = val;
    if (f == 0 && tt < CTX) ct[b * CTX + tt] = val;
  }
}

// ---------------- kernel 2: context LSTM (unchanged, exact fp32) -------------
__global__ void __launch_bounds__(256) ctx_lstm_kernel(
    const float* __restrict__ inp,
    const float* __restrict__ WTx, const float* __restrict__ WT00,
    const float* __restrict__ WT10, const float* __restrict__ WT11,
    const float* __restrict__ bih0, const float* __restrict__ bhh0,
    const float* __restrict__ bih1, const float* __restrict__ bhh1,
    const float* __restrict__ wdf, const float* __restrict__ bdfp,
    const float* __restrict__ wloc, const float* __restrict__ blocp,
    const float* __restrict__ wsc, const float* __restrict__ bscp,
    float* __restrict__ dfo, float* __restrict__ loco, float* __restrict__ sco,
    float* __restrict__ h0f, float* __restrict__ c0f,
    float* __restrict__ h1f, float* __restrict__ c1f)
{
  const int b = blockIdx.x, t = threadIdx.x;
  const int lane = t & 63, w = t >> 6;
  const int gbase = lane << 2;
  __shared__ __align__(16) float gA[4][256];
  __shared__ __align__(16) float gB[4][256];

  const float bs0 = bih0[lane]       + bhh0[lane];
  const float bs1 = bih0[64 + lane]  + bhh0[64 + lane];
  const float bs2 = bih0[128 + lane] + bhh0[128 + lane];
  const float bs3 = bih0[192 + lane] + bhh0[192 + lane];
  const float bs4 = bih1[lane]       + bhh1[lane];
  const float bs5 = bih1[64 + lane]  + bhh1[64 + lane];
  const float bs6 = bih1[128 + lane] + bhh1[128 + lane];
  const float bs7 = bih1[192 + lane] + bhh1[192 + lane];
  const float wdfv = wdf[lane], wlocv = wloc[lane], wscv = wsc[lane];
  const float bdf = bdfp[0], bloc = blocp[0], bsc = bscp[0];

  float h0r = 0.f, h1r = 0.f, c0r = 0.f, c1r = 0.f;
  const float* inb = inp + (size_t)b * TM1 * NIN;
  const int kx = w * 4;    // x-part k-quarter
  const int kh = w * 16;   // h-part k-quarter

  for (int tt = 0; tt < CTX; tt++) {
    float xr = 0.f;
    if (lane < 15) xr = inb[tt * NIN + lane];

    v2f aA = bc2(0.0f), aB = bc2(0.0f);
#pragma unroll
    for (int kk = 0; kk < 4; kk++) {
      const int k = kx + kk;
      const float4 wv = *(const float4*)&WTx[(k << 8) + gbase];
      v2f wlo, whi; wlo[0] = wv.x; wlo[1] = wv.y; whi[0] = wv.z; whi[1] = wv.w;
      const v2f hk = bc2(rl_f(xr, k));
      aA += wlo * hk; aB += whi * hk;
    }
#pragma unroll
    for (int kk = 0; kk < 16; kk++) {
      const int k = kh + kk;
      const float4 wv = *(const float4*)&WT00[(k << 8) + gbase];
      v2f wlo, whi; wlo[0] = wv.x; wlo[1] = wv.y; whi[0] = wv.z; whi[1] = wv.w;
      const v2f hk = bc2(rl_f(h0r, k));
      aA += wlo * hk; aB += whi * hk;
    }
    {
      float4 gv; gv.x = aA[0]; gv.y = aA[1]; gv.z = aB[0]; gv.w = aB[1];
      *(float4*)&gA[w][gbase] = gv;
    }
    __syncthreads();

    {
      float gi = ((gA[0][lane]       + gA[1][lane])       + gA[2][lane])       + gA[3][lane];
      float gf = ((gA[0][64 + lane]  + gA[1][64 + lane])  + gA[2][64 + lane])  + gA[3][64 + lane];
      float gg = ((gA[0][128 + lane] + gA[1][128 + lane]) + gA[2][128 + lane]) + gA[3][128 + lane];
      float go = ((gA[0][192 + lane] + gA[1][192 + lane]) + gA[2][192 + lane]) + gA[3][192 + lane];
      gi += bs0; gf += bs1; gg += bs2; go += bs3;
      c0r = sigm(gf) * c0r + sigm(gi) * tanhf(gg);
      h0r = sigm(go) * tanhf(c0r);
    }

    aA = bc2(0.0f); aB = bc2(0.0f);
#pragma unroll
    for (int kk = 0; kk < 16; kk++) {
      const int k = kh + kk;
      const float4 wv = *(const float4*)&WT10[(k << 8) + gbase];
      v2f wlo, whi; wlo[0] = wv.x; wlo[1] = wv.y; whi[0] = wv.z; whi[1] = wv.w;
      const v2f hk = bc2(rl_f(h0r, k));
      aA += wlo * hk; aB += whi * hk;
    }
#pragma unroll
    for (int kk = 0; kk < 16; kk++) {
      const int k = kh + kk;
      const float4 wv = *(const float4*)&WT11[(k << 8) + gbase];
      v2f wlo, whi; wlo[0] = wv.x; wlo[1] = wv.y; whi[0] = wv.z; whi[1] = wv.w;
      const v2f hk = bc2(rl_f(h1r, k));
      aA += wlo * hk; aB += whi * hk;
    }
    {
      float4 gv; gv.x = aA[0]; gv.y = aA[1]; gv.z = aB[0]; gv.w = aB[1];
      *(float4*)&gB[w][gbase] = gv;
    }
    __syncthreads();

    {
      float gi = ((gB[0][lane]       + gB[1][lane])       + gB[2][lane])       + gB[3][lane];
      float gf = ((gB[0][64 + lane]  + gB[1][64 + lane])  + gB[2][64 + lane])  + gB[3][64 + lane];
      float gg = ((gB[0][128 + lane] + gB[1][128 + lane]) + gB[2][128 + lane]) + gB[3][128 + lane];
      float go = ((gB[0][192 + lane] + gB[1][192 + lane]) + gB[2][192 + lane]) + gB[3][192 + lane];
      gi += bs4; gf += bs5; gg += bs6; go += bs7;
      c1r = sigm(gf) * c1r + sigm(gi) * tanhf(gg);
      h1r = sigm(go) * tanhf(c1r);
      if (w == 0) {
        float pd = h1r * wdfv, pl = h1r * wlocv, ps = h1r * wscv;
#pragma unroll
        for (int off = 32; off > 0; off >>= 1) {
          pd += __shfl_down(pd, off, 64);
          pl += __shfl_down(pl, off, 64);
          ps += __shfl_down(ps, off, 64);
        }
        if (lane == 0) {
          dfo[b * CTX + tt]  = 2.0f + softplusf(pd + bdf);
          loco[b * CTX + tt] = pl + bloc;
          sco[b * CTX + tt]  = softplusf(ps + bsc);
        }
      }
    }
  }
  if (w == 0) {
    h0f[b * 64 + lane] = h0r; c0f[b * 64 + lane] = c0r;
    h1f[b * 64 + lane] = h1r; c1f[b * 64 + lane] = c1r;
  }
}

// ---------------- kernel 3: context sampling (y_ctx) ----------------
__global__ void __launch_bounds__(256) ctx_sample_kernel(
    const float* __restrict__ df, const float* __restrict__ loc, const float* __restrict__ sc,
    const float* __restrict__ tscale, float* __restrict__ yhat,
    u32 kz0, u32 kz1, u32 kg0, u32 kg1)
{
  const int i = blockIdx.x * 256 + threadIdx.x;
  const int r = i / CTX, t = i - r * CTX;
  const int b = r / NSAMP;
  const float dfv = df[b * CTX + t], lv = loc[b * CTX + t], sv = sc[b * CTX + t];
  const float z = normal_from_bits(jx_bits(kz0, kz1, NCTXS, (u32)i));
  u32 gk0, gk1;
  jx_subkey(kg0, kg1, NCTXS, (u32)i, gk0, gk1);
  const float g = jax_gamma_one(gk0, gk1, dfv * 0.5f);
  const float y = (lv + sv * (z * sqrtf(dfv / (2.0f * g)))) * tscale[b];
  yhat[(size_t)r * TM1 + t] = y;
}

// ---------------- kernel 5: persistent decode (MFMA, 256-VGPR budget) --------
// R7: R6 cut spill traffic 3.83->1.30 GB but VGPR_Count stayed 128 (allocator
// ignored __launch_bounds__ min-waves hint).  Two-sided fix: (a) explicit
// amdgpu_flat_work_group_size(512,512) + amdgpu_waves_per_eu(2,2) -> 256-reg
// budget (LDS caps at 1 block/CU anyway); (b) demand cuts in case (a) is
// refused: b1 -> LDS table (-16 regs), xh K-pad shared via one zero row
// (-4 KB LDS), sched_barrier(0) between tq iterations caps transient
// B-frag-read hoisting.  Pre-committed read: VGPR_Count is the tell.
__global__ void __attribute__((amdgpu_flat_work_group_size(512, 512),
                               amdgpu_waves_per_eu(2, 2)))
dec_persist_kernel(
    const float* __restrict__ inp, const float* __restrict__ tscale,
    const f16* __restrict__ WH, const float* __restrict__ emb,
    const float* __restrict__ bih1, const float* __restrict__ bhh1,
    const float* __restrict__ wdf, const float* __restrict__ bdfp,
    const float* __restrict__ wloc, const float* __restrict__ blocp,
    const float* __restrict__ wsc, const float* __restrict__ bscp,
    const float* __restrict__ h0f, const float* __restrict__ c0f,
    const float* __restrict__ h1f, const float* __restrict__ c1f,
    const float* __restrict__ ct, const float* __restrict__ RND,
    float* __restrict__ yhat, u32 kl0, u32 kl1)
{
  const int t    = threadIdx.x;
  const int lane = t & 63;
  const int w    = t >> 6;        // wave 0..7
  const int r0   = w * RPW;       // wave's first local row
  const int c16  = lane & 15;     // gate col within tile / A row select
  const int kg   = lane >> 4;     // k-group / D row-group

  __shared__ __align__(16) f16   wgt[WH_TOT];        // 104 KB B-fragment weights
  __shared__ __align__(16) f16   h0h[DROWS * HSTR];  // 18 KB
  __shared__ __align__(16) f16   h1h[DROWS * HSTR];  // 18 KB
  __shared__ __align__(16) f16   xh[DROWS][16];      // 4 KB (x features; [15]=1.0)
  __shared__ __align__(16) f16   xzero[32];          // shared K-pad zeros
  __shared__ __align__(16) f16   hist[DROWS][32];    // 8 KB lag ring
  __shared__ __align__(16) f16   fst[3][NSTEP][2];   // X ch2 / ch1 stash
  __shared__ __align__(16) float hw[3][64];          // head weights (df/loc/sc)
  __shared__ __align__(16) float b1L[4][4][16];      // layer-1 bias table, 1 KB
  __shared__ float tsr[DROWS];
  __shared__ float dfL[DROWS], locL[DROWS], scL[DROWS];
  __shared__ unsigned char rsel[DROWS];

  const int base = blockIdx.x * DROWS;
  const int bblo = base / NSAMP;

  // ---- stage all weights once: 13 x (8 waves x 64 lanes x 16B) ----
#pragma unroll
  for (int i = 0; i < 13; i++) {
    const int off = (i * 8 + w) * 512;   // halves
    __builtin_amdgcn_global_load_lds(
        (const __attribute__((address_space(1))) void*)(WH + off + lane * 8),
        (__attribute__((address_space(3))) void*)(wgt + off), 16, 0, 0);
  }

  const float bdf = bdfp[0], bloc = blocp[0], bsc = bscp[0];
  const float embv = emb[0];

  float c0reg[4][4], c1reg[4][4];
#pragma unroll
  for (int rr = 0; rr < 4; rr++) {
    const int row = r0 + kg * 4 + rr;
    const int bb = (base + row) / NSAMP;
#pragma unroll
    for (int tq = 0; tq < 4; tq++) {
      c0reg[rr][tq] = c0f[bb * 64 + tq * 16 + c16];
      c1reg[rr][tq] = c1f[bb * 64 + tq * 16 + c16];
    }
  }

  // ---- h state into LDS (stride HSTR) ----
  for (int idx = t; idx < DROWS * 64; idx += 512) {
    const int row = idx >> 6, hid = idx & 63;
    const int bb = (base + row) / NSAMP;
    h0h[row * HSTR + hid] = (f16)h0f[bb * 64 + hid];
    h1h[row * HSTR + hid] = (f16)h1f[bb * 64 + hid];
  }

  for (int idx = t; idx < DROWS * 28; idx += 512) {
    const int i = idx / 28, k = idx - i * 28;
    const int bb = (base + i) / NSAMP;
    hist[i][31 - k] = (f16)ct[bb * CTX + 335 - k];
  }
  // feature stash (X ch2 @f=12, X ch1 @f=14); block spans <=3 batch indices
  for (int idx = t; idx < 3 * NSTEP * 2; idx += 512) {
    const int sel = idx / (NSTEP * 2), rem = idx - sel * (NSTEP * 2);
    const int s = rem >> 1, f = rem & 1;
    const int bb = min(bblo + sel, NB - 1);
    fst[sel][s][f] = (f16)inp[((size_t)bb * TM1 + CTX + s) * NIN + (f ? 14 : 12)];
  }
  if (t < 64)        hw[0][t]       = wdf[t];
  else if (t < 128)  hw[1][t - 64]  = wloc[t - 64];
  else if (t < 192)  hw[2][t - 128] = wsc[t - 128];
  else if (t < 448) {
    const int g = t - 192;                 // 0..255
    const int gq = g >> 6, rem = g & 63;
    b1L[gq][rem >> 4][rem & 15] = bih1[g] + bhh1[g];
  } else if (t < 480) {
    xzero[t - 448] = (f16)0.0f;            // shared K-pad zero row
  }
  if (t < DROWS) {
    const int rg = base + t;
    tsr[t] = tscale[rg / NSAMP];
    xh[t][15] = (f16)1.0f;                 // bias lane (W[k=15]=b0)
    rsel[t] = (unsigned char)((rg / NSAMP) - bblo);
  }
  float prevreg = 0.f;
  if (lane < RPW) prevreg = yhat[(size_t)(base + r0 + lane) * TM1 + 335];
  __syncthreads();   // covers weight staging (vmcnt drain) + all init writes

  const int arow = r0 + c16;         // A-fragment row for this lane
  // x A-frag source: kg 0,1 read the 16 real slots; kg 2,3 read shared zeros
  const f16* axp = (kg < 2) ? &xh[arow][kg * 8] : &xzero[(kg - 2) * 8];

#define BFR(off) (*(const half8*)&wgt[(off) + lane * 8])

  for (int s = 0; s < NSTEP; s++) {
    // ---- parallel x-build (slots 0..14; 15 stays 1.0) ----
    if (lane < RPW) {
      const int row = r0 + lane;
      const float nv = prevreg / tsr[row];
      const f16 nh = (f16)nv;
      xh[row][0] = nh;
      hist[row][s & 31] = nh;
    }
    {
      const int rq = lane >> 2, q = lane & 3;
      const int row = r0 + rq;
#pragma unroll
      for (int p = 0; p < 4; p++) {
        const int sl = 1 + q + p * 4;          // 1..16
        if (sl <= 10) {
          xh[row][sl] = hist[row][(s - c_LAGS[sl - 1]) & 31];
        } else if (sl == 11) {
          xh[row][sl] = (f16)embv;
        } else if (sl == 12) {
          xh[row][sl] = fst[rsel[row]][s][0];
        } else if (sl == 13) {
          xh[row][sl] = (f16)logf(tsr[row]);
        } else if (sl == 14) {
          xh[row][sl] = fst[rsel[row]][s][1];
        }
      }
    }

    // ---- layer 0: A-frags, then per-gate-column (tq) MFMA + cell ----
    const half8 ax  = *(const half8*)axp;
    const half8 a00 = *(const half8*)&h0h[arow * HSTR + kg * 8];
    const half8 a01 = *(const half8*)&h0h[arow * HSTR + 32 + kg * 8];
#pragma unroll
    for (int tq = 0; tq < 4; tq++) {
      floatx4 ai = {0.f, 0.f, 0.f, 0.f};
      floatx4 af = {0.f, 0.f, 0.f, 0.f};
      floatx4 ag = {0.f, 0.f, 0.f, 0.f};
      floatx4 ao = {0.f, 0.f, 0.f, 0.f};
      ai = __builtin_amdgcn_mfma_f32_16x16x32_f16(ax, BFR(WH_X + (tq)      * 256), ai, 0, 0, 0);
      af = __builtin_amdgcn_mfma_f32_16x16x32_f16(ax, BFR(WH_X + (4 + tq)  * 256), af, 0, 0, 0);
      ag = __builtin_amdgcn_mfma_f32_16x16x32_f16(ax, BFR(WH_X + (8 + tq)  * 256), ag, 0, 0, 0);
      ao = __builtin_amdgcn_mfma_f32_16x16x32_f16(ax, BFR(WH_X + (12 + tq) * 256), ao, 0, 0, 0);
      ai = __builtin_amdgcn_mfma_f32_16x16x32_f16(a00, BFR(WH_00 + ((tq) * 2 + 0)      * 512), ai, 0, 0, 0);
      ai = __builtin_amdgcn_mfma_f32_16x16x32_f16(a01, BFR(WH_00 + ((tq) * 2 + 1)      * 512), ai, 0, 0, 0);
      af = __builtin_amdgcn_mfma_f32_16x16x32_f16(a00, BFR(WH_00 + ((4 + tq) * 2 + 0)  * 512), af, 0, 0, 0);
      af = __builtin_amdgcn_mfma_f32_16x16x32_f16(a01, BFR(WH_00 + ((4 + tq) * 2 + 1)  * 512), af, 0, 0, 0);
      ag = __builtin_amdgcn_mfma_f32_16x16x32_f16(a00, BFR(WH_00 + ((8 + tq) * 2 + 0)  * 512), ag, 0, 0, 0);
      ag = __builtin_amdgcn_mfma_f32_16x16x32_f16(a01, BFR(WH_00 + ((8 + tq) * 2 + 1)  * 512), ag, 0, 0, 0);
      ao = __builtin_amdgcn_mfma_f32_16x16x32_f16(a00, BFR(WH_00 + ((12 + tq) * 2 + 0) * 512), ao, 0, 0, 0);
      ao = __builtin_amdgcn_mfma_f32_16x16x32_f16(a01, BFR(WH_00 + ((12 + tq) * 2 + 1) * 512), ao, 0, 0, 0);
#pragma unroll
      for (int rr = 0; rr < 4; rr++) {
        const float gi = ai[rr], gf = af[rr], gg = ag[rr], go = ao[rr];
        float cc = c0reg[rr][tq];
        cc = sigm(gf) * cc + sigm(gi) * tanhf(gg);
        c0reg[rr][tq] = cc;
        h0h[(r0 + kg * 4 + rr) * HSTR + tq * 16 + c16] = (f16)(sigm(go) * tanhf(cc));
      }
      __builtin_amdgcn_sched_barrier(0);   // cap cross-tq hoisting (reg pressure)
    }

    // ---- layer 1: A-frags (h0_new complete), per-tq MFMA + cell + head ----
    const half8 a10a = *(const half8*)&h0h[arow * HSTR + kg * 8];
    const half8 a10b = *(const half8*)&h0h[arow * HSTR + 32 + kg * 8];
    const half8 a11a = *(const half8*)&h1h[arow * HSTR + kg * 8];
    const half8 a11b = *(const half8*)&h1h[arow * HSTR + 32 + kg * 8];
    float pd[4] = {0.f, 0.f, 0.f, 0.f};
    float pl[4] = {0.f, 0.f, 0.f, 0.f};
    float ps[4] = {0.f, 0.f, 0.f, 0.f};
#pragma unroll
    for (int tq = 0; tq < 4; tq++) {
      const float bi = b1L[0][tq][c16];
      const float bf = b1L[1][tq][c16];
      const float bg = b1L[2][tq][c16];
      const float bo = b1L[3][tq][c16];
      floatx4 ai = {bi, bi, bi, bi};
      floatx4 af = {bf, bf, bf, bf};
      floatx4 ag = {bg, bg, bg, bg};
      floatx4 ao = {bo, bo, bo, bo};
      ai = __builtin_amdgcn_mfma_f32_16x16x32_f16(a10a, BFR(WH_10 + ((tq) * 2 + 0)      * 512), ai, 0, 0, 0);
      ai = __builtin_amdgcn_mfma_f32_16x16x32_f16(a10b, BFR(WH_10 + ((tq) * 2 + 1)      * 512), ai, 0, 0, 0);
      ai = __builtin_amdgcn_mfma_f32_16x16x32_f16(a11a, BFR(WH_11 + ((tq) * 2 + 0)      * 512), ai, 0, 0, 0);
      ai = __builtin_amdgcn_mfma_f32_16x16x32_f16(a11b, BFR(WH_11 + ((tq) * 2 + 1)      * 512), ai, 0, 0, 0);
      af = __builtin_amdgcn_mfma_f32_16x16x32_f16(a10a, BFR(WH_10 + ((4 + tq) * 2 + 0)  * 512), af, 0, 0, 0);
      af = __builtin_amdgcn_mfma_f32_16x16x32_f16(a10b, BFR(WH_10 + ((4 + tq) * 2 + 1)  * 512), af, 0, 0, 0);
      af = __builtin_amdgcn_mfma_f32_16x16x32_f16(a11a, BFR(WH_11 + ((4 + tq) * 2 + 0)  * 512), af, 0, 0, 0);
      af = __builtin_amdgcn_mfma_f32_16x16x32_f16(a11b, BFR(WH_11 + ((4 + tq) * 2 + 1)  * 512), af, 0, 0, 0);
      ag = __builtin_amdgcn_mfma_f32_16x16x32_f16(a10a, BFR(WH_10 + ((8 + tq) * 2 + 0)  * 512), ag, 0, 0, 0);
      ag = __builtin_amdgcn_mfma_f32_16x16x32_f16(a10b, BFR(WH_10 + ((8 + tq) * 2 + 1)  * 512), ag, 0, 0, 0);
      ag = __builtin_amdgcn_mfma_f32_16x16x32_f16(a11a, BFR(WH_11 + ((8 + tq) * 2 + 0)  * 512), ag, 0, 0, 0);
      ag = __builtin_amdgcn_mfma_f32_16x16x32_f16(a11b, BFR(WH_11 + ((8 + tq) * 2 + 1)  * 512), ag, 0, 0, 0);
      ao = __builtin_amdgcn_mfma_f32_16x16x32_f16(a10a, BFR(WH_10 + ((12 + tq) * 2 + 0) * 512), ao, 0, 0, 0);
      ao = __builtin_amdgcn_mfma_f32_16x16x32_f16(a10b, BFR(WH_10 + ((12 + tq) * 2 + 1) * 512), ao, 0, 0, 0);
      ao = __builtin_amdgcn_mfma_f32_16x16x32_f16(a11a, BFR(WH_11 + ((12 + tq) * 2 + 0) * 512), ao, 0, 0, 0);
      ao = __builtin_amdgcn_mfma_f32_16x16x32_f16(a11b, BFR(WH_11 + ((12 + tq) * 2 + 1) * 512), ao, 0, 0, 0);
      const float hwd = hw[0][tq * 16 + c16];
      const float hwl = hw[1][tq * 16 + c16];
      const float hws = hw[2][tq * 16 + c16];
#pragma unroll
      for (int rr = 0; rr < 4; rr++) {
        const float gi = ai[rr], gf = af[rr], gg = ag[rr], go = ao[rr];
        float cc = c1reg[rr][tq];
        cc = sigm(gf) * cc + sigm(gi) * tanhf(gg);
        c1reg[rr][tq] = cc;
        const float h1v = sigm(go) * tanhf(cc);
        h1h[(r0 + kg * 4 + rr) * HSTR + tq * 16 + c16] = (f16)h1v;
        pd[rr] += h1v * hwd;
        pl[rr] += h1v * hwl;
        ps[rr] += h1v * hws;
      }
      __builtin_amdgcn_sched_barrier(0);   // cap cross-tq hoisting (reg pressure)
    }
    // reduce across the 16 cols (lanes share kg within width-16 groups)
#pragma unroll
    for (int rr = 0; rr < 4; rr++) {
#pragma unroll
      for (int off = 8; off >= 1; off >>= 1) {
        pd[rr] += __shfl_xor(pd[rr], off, 16);
        pl[rr] += __shfl_xor(pl[rr], off, 16);
        ps[rr] += __shfl_xor(ps[rr], off, 16);
      }
    }
    if (c16 == 0) {
#pragma unroll
      for (int rr = 0; rr < 4; rr++) {
        const int row = r0 + kg * 4 + rr;
        dfL[row]  = 2.0f + softplusf(pd[rr] + bdf);
        locL[row] = pl[rr] + bloc;
        scL[row]  = softplusf(ps[rr] + bsc);
      }
    }

    // ---- sample (one lane per row, 16 rows in parallel) ----
    if (lane < RPW) {
      const int row = r0 + lane, rg = base + row;
      const float4 R = *(const float4*)(RND + ((size_t)s * RTOT + rg) * 4);
      const float dfv = dfL[row], lv = locL[row], scv = scL[row];
      const float z = R.x;
      const float alpha = dfv * 0.5f;
      float gam;
      {
#pragma clang fp contract(off)
        const float d = alpha - 0.33333334f;
        const float c = 0.33333334f / sqrtf(d);
        float x = R.y;
        float v = 1.0f + x * c;
        bool ok = true;
        if (v <= 0.0f) { x = R.z; v = 1.0f + x * c; ok = (v > 0.0f); }
        const float X = x * x;
        const float V = (v * v) * v;
        const float U = R.w;
        bool accept = false;
        if (ok) {
          if (!(U >= 1.0f - 0.0331f * (X * X))) accept = true;
          else if (!(logf(U) >= 0.5f * X + d * ((1.0f - V) + logf(V)))) accept = true;
        }
        if (accept) {
          gam = d * V;
        } else {
          u32 ks0, ks1, skg0, skg1, gk0, gk1;
          tf2x32(kl0, kl1, 0u, (u32)s, ks0, ks1);
          tf2x32(ks0, ks1, 0u, 1u, skg0, skg1);
          jx_subkey(skg0, skg1, RTOT, (u32)rg, gk0, gk1);
          gam = jax_gamma_one(gk0, gk1, alpha);
        }
      }
      const float y = (lv + scv * (z * sqrtf(dfv / (2.0f * gam)))) * tsr[row];
      yhat[(size_t)rg * TM1 + CTX + s] = y;
      prevreg = y;
    }
  }
#undef BFR
}

// ---------------- kernel 6: median over 100 samples per (b,t) ----------------
__global__ void __launch_bounds__(256) median_kernel(
    const float* __restrict__ yhat, float* __restrict__ out)
{
  __shared__ float vals[4][100];
  const int wave = threadIdx.x >> 6, lane = threadIdx.x & 63;
  const int cell = blockIdx.x * 4 + wave;
  const int b = cell / TM1, t = cell - b * TM1;
  const float* basep = yhat + (size_t)b * NSAMP * TM1 + t;
  const float v1 = basep[(size_t)lane * TM1];
  vals[wave][lane] = v1;
  float v2 = 0.f;
  if (lane < 36) { v2 = basep[(size_t)(64 + lane) * TM1]; vals[wave][64 + lane] = v2; }
  __syncthreads();
  int cl1 = 0, ce1 = 0, cl2 = 0, ce2 = 0;
  for (int jj = 0; jj < 100; jj++) {
    const float w = vals[wave][jj];
    cl1 += (w < v1); ce1 += (w == v1);
    cl2 += (w < v2); ce2 += (w == v2);
  }
  if (cl1 <= 49 && 49 < cl1 + ce1) out[cell] = v1;
  if (lane < 36 && cl2 <= 49 && 49 < cl2 + ce2) out[cell] = v2;
}

// ---------------- launch ----------------
extern "C" void kernel_launch(void* const* d_in, const int* in_sizes, int n_in,
                              void* d_out, int out_size, void* d_ws, size_t ws_size,
                              hipStream_t stream) {
  (void)in_sizes; (void)n_in; (void)out_size; (void)ws_size;
  const float* X     = (const float*)d_in[0];
  const float* Wih0  = (const float*)d_in[2];
  const float* Whh0  = (const float*)d_in[3];
  const float* bih0  = (const float*)d_in[4];
  const float* bhh0  = (const float*)d_in[5];
  const float* Wih1  = (const float*)d_in[6];
  const float* Whh1  = (const float*)d_in[7];
  const float* bih1  = (const float*)d_in[8];
  const float* bhh1  = (const float*)d_in[9];
  const float* wdf   = (const float*)d_in[10];
  const float* bdf   = (const float*)d_in[11];
  const float* wloc  = (const float*)d_in[12];
  const float* bloc  = (const float*)d_in[13];
  const float* wsc   = (const float*)d_in[14];
  const float* bsc   = (const float*)d_in[15];
  const float* emb   = (const float*)d_in[16];

  float* wsf = (float*)d_ws;
  float* inp  = wsf + OFF_INP;
  float* ct   = wsf + OFF_CT;
  float* ts   = wsf + OFF_TS;
  float* lts  = wsf + OFF_LTS;
  float* dfp  = wsf + OFF_DF;
  float* locp = wsf + OFF_LOC;
  float* scp  = wsf + OFF_SC;
  float* h0f  = wsf + OFF_H0F;
  float* c0f  = wsf + OFF_C0F;
  float* h1f  = wsf + OFF_H1F;
  float* c1f  = wsf + OFF_C1F;
  float* yhat = wsf + OFF_YH;
  float* wtx  = wsf + OFF_WTX;
  float* wt00 = wsf + OFF_WT00;
  float* wt10 = wsf + OFF_WT10;
  float* wt11 = wsf + OFF_WT11;
  f16*   wh   = (f16*)(wsf + OFF_WH);
  float* rnd  = wsf + OFF_RND;

  const u32 key0 = 0u, key1 = 42u;
  u32 kc0, kc1, kl0, kl1;
  jx_subkey(key0, key1, 2u, 0u, kc0, kc1);
  jx_subkey(key0, key1, 2u, 1u, kl0, kl1);
  u32 kz0, kz1, kg0, kg1;
  jx_subkey(kc0, kc1, 2u, 0u, kz0, kz1);
  jx_subkey(kc0, kc1, 2u, 1u, kg0, kg1);

  wtrans_kernel<<<208, 256, 0, stream>>>(Wih0, Whh0, Wih1, Whh1, wtx, wt00, wt10, wt11);
  wh_kernel<<<208, 256, 0, stream>>>(Wih0, Whh0, Wih1, Whh1, bih0, bhh0, wh);
  rnd_dec_kernel<<<(NSTEP * RTOT) / 256, 256, 0, stream>>>(rnd, kl0, kl1);
  prep_kernel<<<NB, 256, 0, stream>>>(X, emb, inp, ct, ts, lts);
  ctx_lstm_kernel<<<NB, 256, 0, stream>>>(inp, wtx, wt00, wt10, wt11,
                                          bih0, bhh0, bih1, bhh1,
                                          wdf, bdf, wloc, bloc, wsc, bsc,
                                          dfp, locp, scp, h0f, c0f, h1f, c1f);
  ctx_sample_kernel<<<NCTXS / 256, 256, 0, stream>>>(dfp, locp, scp, ts, yhat, kz0, kz1, kg0, kg1);
  dec_persist_kernel<<<DBLOCKS, 512, 0, stream>>>(inp, ts, wh, emb,
                                                  bih1, bhh1,
                                                  wdf, bdf, wloc, bloc, wsc, bsc,
                                                  h0f, c0f, h1f, c1f, ct, rnd, yhat, kl0, kl1);
  median_kernel<<<(NB * TM1) / 4, 256, 0, stream>>>(yhat, (float*)d_out);
}

// Round 9
// 2064.406 us; speedup vs baseline: 1.7500x; 1.2062x over previous
//
#include <hip/hip_runtime.h>
#include <stdint.h>
#include <stddef.h>

typedef uint32_t u32;
typedef float v2f __attribute__((ext_vector_type(2)));
typedef _Float16 f16;
typedef f16 half8 __attribute__((ext_vector_type(8)));
typedef float floatx4 __attribute__((ext_vector_type(4)));

// ---------------- problem constants (fixed by reference file) ----------------
#define NB    256      // batch B
#define LFULL 412      // L
#define NCH   3        // C
#define CTX   336      // context_length
#define NSAMP 100      // n_samples
#define TM1   383      // T-1 (T = L - MAX_LAG = 384)
#define HID   64
#define NIN   15
#define RTOT  25600    // NB*NSAMP
#define NCTXS 8601600u // RTOT*CTX
#define NSTEP 47       // H-1

#define DROWS   128    // rows per persistent decode block (16 per wave, 8 waves)
#define RPW     16     // rows per wave
#define DBLOCKS (RTOT / DROWS)  // 200 -> 1 dispatch round on 256 CUs

#define HSTR    72     // h-array LDS stride in halves (144 B, 16B-aligned, bank-spread)

#define JAX_PARTITIONABLE 1

__device__ const int c_LAGS[10] = {1,2,3,4,5,6,7,14,21,28};

__device__ inline v2f bc2(float x) { v2f r; r[0] = x; r[1] = x; return r; }

// ---------------- threefry2x32 (matches jax._src.prng) ----------------
__host__ __device__ inline void tf2x32(u32 k0, u32 k1, u32 x0, u32 x1, u32& o0, u32& o1) {
  const u32 ks2 = k0 ^ k1 ^ 0x1BD11BDAu;
#define TFR(r) { x0 += x1; x1 = (x1 << (r)) | (x1 >> (32 - (r))); x1 ^= x0; }
  x0 += k0; x1 += k1;
  TFR(13) TFR(15) TFR(26) TFR(6)
  x0 += k1; x1 += ks2 + 1u;
  TFR(17) TFR(29) TFR(16) TFR(24)
  x0 += ks2; x1 += k0 + 2u;
  TFR(13) TFR(15) TFR(26) TFR(6)
  x0 += k0; x1 += k1 + 3u;
  TFR(17) TFR(29) TFR(16) TFR(24)
  x0 += k1; x1 += ks2 + 4u;
  TFR(13) TFR(15) TFR(26) TFR(6)
  x0 += ks2; x1 += k0 + 5u;
#undef TFR
  o0 = x0; o1 = x1;
}

__host__ __device__ inline u32 split_word_legacy(u32 k0, u32 k1, u32 n, u32 j) {
  u32 o0, o1;
  if (j < n) { tf2x32(k0, k1, j, n + j, o0, o1); return o0; }
  tf2x32(k0, k1, j - n, j, o0, o1); return o1;
}

__host__ __device__ inline void jx_subkey(u32 k0, u32 k1, u32 n, u32 i, u32& s0, u32& s1) {
#if JAX_PARTITIONABLE
  (void)n; tf2x32(k0, k1, 0u, i, s0, s1);
#else
  s0 = split_word_legacy(k0, k1, n, 2u * i);
  s1 = split_word_legacy(k0, k1, n, 2u * i + 1u);
#endif
}

__device__ inline u32 jx_bits(u32 k0, u32 k1, u32 n, u32 i) {
#if JAX_PARTITIONABLE
  (void)n; u32 o0, o1; tf2x32(k0, k1, 0u, i, o0, o1); return o0 ^ o1;
#else
  u32 o0, o1;
  if (n == 1u) { tf2x32(k0, k1, 0u, 0u, o0, o1); return o0; }
  const u32 h = n >> 1;
  if (i < h) { tf2x32(k0, k1, i, h + i, o0, o1); return o0; }
  tf2x32(k0, k1, i - h, i, o0, o1); return o1;
#endif
}

// ---------------- JAX-exact float transforms ----------------
__device__ inline float jax_erfinv(float x) {
#pragma clang fp contract(off)
  float w = -log1pf(-x * x);
  float p;
  if (w < 5.0f) {
    w = w - 2.5f;
    p = 2.81022636e-08f;
    p = 3.43273939e-07f + p * w;
    p = -3.5233877e-06f + p * w;
    p = -4.39150654e-06f + p * w;
    p = 0.00021858087f + p * w;
    p = -0.00125372503f + p * w;
    p = -0.00417768164f + p * w;
    p = 0.246640727f + p * w;
    p = 1.50140941f + p * w;
  } else {
    w = sqrtf(w) - 3.0f;
    p = -0.000200214257f;
    p = 0.000100950558f + p * w;
    p = 0.00134934322f + p * w;
    p = -0.00367342844f + p * w;
    p = 0.00573950773f + p * w;
    p = -0.0076224613f + p * w;
    p = 0.00943887047f + p * w;
    p = 1.00167406f + p * w;
    p = 2.83297682f + p * w;
  }
  return p * x;
}

__device__ inline float u01_from_bits(u32 bits) {
  return __uint_as_float((bits >> 9) | 0x3f800000u) - 1.0f;
}

__device__ inline float normal_from_bits(u32 bits) {
#pragma clang fp contract(off)
  const float lo = -0.99999994f;
  const float u = u01_from_bits(bits);
  float r = u * 2.0f + lo;
  r = fmaxf(lo, r);
  return 1.41421356f * jax_erfinv(r);
}

__device__ float jax_gamma_one(u32 k0, u32 k1, float alpha) {
#pragma clang fp contract(off)
  const bool boost_mask = (alpha >= 1.0f);
  const float alpha_orig = alpha;
  const float a = boost_mask ? alpha : (alpha + 1.0f);
  const float d = a - 0.33333334f;
  const float c = 0.33333334f / sqrtf(d);
  u32 K0, K1, S0, S1;
  jx_subkey(k0, k1, 2u, 0u, K0, K1);
  jx_subkey(k0, k1, 2u, 1u, S0, S1);
  float u_boost = 1.0f;
  if (!boost_mask) u_boost = u01_from_bits(jx_bits(S0, S1, 1u, 0u));
  float X = 0.0f, V = 1.0f, U = 2.0f;
  while (true) {
    if (!(U >= 1.0f - 0.0331f * (X * X))) break;
    if (!(logf(U) >= 0.5f * X + d * ((1.0f - V) + logf(V)))) break;
    u32 nk0, nk1, xk0, xk1, uk0, uk1;
    jx_subkey(K0, K1, 3u, 0u, nk0, nk1);
    jx_subkey(K0, K1, 3u, 1u, xk0, xk1);
    jx_subkey(K0, K1, 3u, 2u, uk0, uk1);
    K0 = nk0; K1 = nk1;
    float x, v;
    u32 c0 = xk0, c1 = xk1;
    do {
      u32 t0, t1, s0, s1;
      jx_subkey(c0, c1, 2u, 0u, t0, t1);
      jx_subkey(c0, c1, 2u, 1u, s0, s1);
      c0 = t0; c1 = t1;
      x = normal_from_bits(jx_bits(s0, s1, 1u, 0u));
      v = 1.0f + x * c;
    } while (v <= 0.0f);
    X = x * x;
    V = (v * v) * v;
    U = u01_from_bits(jx_bits(uk0, uk1, 1u, 0u));
  }
  const float sample = d * V;
  const float boost = boost_mask ? 1.0f : powf(u_boost, 1.0f / alpha_orig);
  return sample * boost;
}

// R8: HW-native sigmoid/tanh (v_exp_f32 + v_rcp_f32, ~4-5 insts vs 10-20 libm).
// absmax has been pinned at 2^-10 (output bf16 quantization) across all rounds
// -> ~1e-6 approx error is far inside slack.  Used in LSTM cells only.
__device__ inline float sigm(float x) {
  return __builtin_amdgcn_rcpf(1.0f + exp2f(-1.44269504f * x));
}
__device__ inline float tanh_fast(float x) {
  const float e = exp2f(2.88539008f * x);
  return 1.0f - 2.0f * __builtin_amdgcn_rcpf(e + 1.0f);
}
__device__ inline float softplusf(float x) { return fmaxf(x, 0.0f) + log1pf(expf(-fabsf(x))); }

// cross-lane broadcast on the VALU pipe (not DS): v_readlane -> SGPR (ctx kernel)
__device__ inline float rl_f(float v, int l) {
  return __int_as_float(__builtin_amdgcn_readlane(__float_as_int(v), l));
}

// ---------------- workspace layout (floats) ----------------
enum : size_t {
  OFF_INP  = 0,
  OFF_CT   = OFF_INP + (size_t)NB * TM1 * NIN,
  OFF_TS   = OFF_CT + (size_t)NB * CTX,
  OFF_LTS  = OFF_TS + NB,
  OFF_DF   = OFF_LTS + NB,
  OFF_LOC  = OFF_DF + (size_t)NB * CTX,
  OFF_SC   = OFF_LOC + (size_t)NB * CTX,
  OFF_H0F  = OFF_SC + (size_t)NB * CTX,
  OFF_C0F  = OFF_H0F + (size_t)NB * HID,
  OFF_H1F  = OFF_C0F + (size_t)NB * HID,
  OFF_C1F  = OFF_H1F + (size_t)NB * HID,
  OFF_YH   = OFF_C1F + (size_t)NB * HID,
  OFF_WTX  = OFF_YH + (size_t)RTOT * TM1,     // Wih0^T padded [16][256] (ctx kernel)
  OFF_WT00 = OFF_WTX + 4096,                  // Whh0^T [64][256]
  OFF_WT10 = OFF_WT00 + 16384,                // Wih1^T [64][256]
  OFF_WT11 = OFF_WT10 + 16384,                // Whh1^T [64][256]
  OFF_WH   = OFF_WT11 + 16384,                // fp16 MFMA-fragment weights, 54272 halves
  OFF_RND  = OFF_WH + 27136,                  // decode randoms [NSTEP][RTOT][4]
  WS_FLOATS = OFF_RND + (size_t)NSTEP * RTOT * 4
};

// fp16 weight blob segment offsets (in halves)
#define WH_X   0        // layer0 x-part: 16 nt x (32 lanes x 8 halves); k=15 = bias0 (x[15]=1)
#define WH_00  4096     // layer0 h-part: 16 nt x 2 kchunk x (64 x 8)   16x16x32 B-frags
#define WH_10  20480    // layer1 h0-part
#define WH_11  36864    // layer1 h1-part
#define WH_HD  53248    // head: 2 kchunk x (64 x 8); cols 0/1/2 = wdf/wloc/wsc
#define WH_TOT 54272

// ---------------- kernel 0a: transpose weights (fp32, ctx kernel) -----------
__global__ void __launch_bounds__(256) wtrans_kernel(
    const float* __restrict__ Wih0, const float* __restrict__ Whh0,
    const float* __restrict__ Wih1, const float* __restrict__ Whh1,
    float* __restrict__ WTx, float* __restrict__ WT00,
    float* __restrict__ WT10, float* __restrict__ WT11)
{
  const int i = blockIdx.x * 256 + threadIdx.x;   // < 53248
  if (i < 4096) {
    const int k = i >> 8, g = i & 255;
    WTx[i] = (k < 15) ? Wih0[g * 15 + k] : 0.0f;
  } else if (i < 4096 + 16384) {
    const int j = i - 4096, k = j >> 8, g = j & 255;
    WT00[j] = Whh0[g * 64 + k];
  } else if (i < 4096 + 32768) {
    const int j = i - 4096 - 16384, k = j >> 8, g = j & 255;
    WT10[j] = Wih1[g * 64 + k];
  } else {
    const int j = i - 4096 - 32768, k = j >> 8, g = j & 255;
    WT11[j] = Whh1[g * 64 + k];
  }
}

// ---------------- kernel 0a2: fp16 MFMA B-fragment weights for decode --------
// All fragments use the verified shape 16x16x32 (m89/m97 family):
//  h-part:  lane l holds B[k=kc*32+(l>>4)*8+e][n=nt*16+(l&15)], e=0..7 (16B/lane)
//  x-part:  K=32 zero-padded; lanes 0..31 carry k=0..15; k==15 slot = layer-0
//           bias (bih0+bhh0), paired with xh[row][15]=1.0.
//  head:    R8 — cols 0/1/2 = wdf/wloc/wsc over k=0..63 (2 kchunks); the head
//           projection becomes 2 MFMAs (deletes 48 shfl_xor x3 + 48 fma).
__global__ void __launch_bounds__(256) wh_kernel(
    const float* __restrict__ Wih0, const float* __restrict__ Whh0,
    const float* __restrict__ Wih1, const float* __restrict__ Whh1,
    const float* __restrict__ bih0, const float* __restrict__ bhh0,
    const float* __restrict__ wdf, const float* __restrict__ wloc,
    const float* __restrict__ wsc,
    f16* __restrict__ WH)
{
  const int j = blockIdx.x * 256 + threadIdx.x;   // < 54272
  if (j < WH_00) {
    const int nt = j >> 8, rem = j & 255;
    const int l = rem >> 3, e = rem & 7;          // l = 0..31
    const int g = nt * 16 + (l & 15);
    const int k = (l >> 4) * 8 + e;               // k = 0..15
    WH[j] = (f16)((k < 15) ? Wih0[g * 15 + k] : (bih0[g] + bhh0[g]));
  } else if (j < WH_HD) {
    const float* W; int q;
    if (j < WH_10)      { W = Whh0; q = j - WH_00; }
    else if (j < WH_11) { W = Wih1; q = j - WH_10; }
    else                { W = Whh1; q = j - WH_11; }
    const int blk = q >> 9, rem = q & 511;   // blk = nt*2 + kc
    const int l = rem >> 3, e = rem & 7;
    const int nt = blk >> 1, kc = blk & 1;
    const int g = nt * 16 + (l & 15);
    const int k = kc * 32 + (l >> 4) * 8 + e;
    WH[j] = (f16)W[g * 64 + k];
  } else {
    const int q = j - WH_HD;
    const int kc = q >> 9, rem = q & 511;
    const int l = rem >> 3, e = rem & 7;
    const int n = l & 15;
    const int k = kc * 32 + (l >> 4) * 8 + e;
    float v = 0.0f;
    if (n == 0)      v = wdf[k];
    else if (n == 1) v = wloc[k];
    else if (n == 2) v = wsc[k];
    WH[j] = (f16)v;
  }
}

// ---------------- kernel 0b: precompute decode randoms -----------------------
__global__ void __launch_bounds__(256) rnd_dec_kernel(
    float* __restrict__ RND, u32 kl0, u32 kl1)
{
  const int i = blockIdx.x * 256 + threadIdx.x;   // < NSTEP*RTOT = 1203200
  const int s = i / RTOT, rg = i - s * RTOT;
  u32 ks0, ks1, skz0, skz1, skg0, skg1;
  tf2x32(kl0, kl1, 0u, (u32)s, ks0, ks1);
  tf2x32(ks0, ks1, 0u, 0u, skz0, skz1);
  tf2x32(ks0, ks1, 0u, 1u, skg0, skg1);
  const float z = normal_from_bits(jx_bits(skz0, skz1, RTOT, (u32)rg));
  u32 gk0, gk1;
  jx_subkey(skg0, skg1, RTOT, (u32)rg, gk0, gk1);
  u32 K0, K1, S0, S1;
  jx_subkey(gk0, gk1, 2u, 0u, K0, K1);
  jx_subkey(gk0, gk1, 2u, 1u, S0, S1);   // boost key, unused (alpha >= 1)
  u32 nk0, nk1, xk0, xk1, uk0, uk1;
  jx_subkey(K0, K1, 3u, 0u, nk0, nk1);
  jx_subkey(K0, K1, 3u, 1u, xk0, xk1);
  jx_subkey(K0, K1, 3u, 2u, uk0, uk1);
  u32 c0 = xk0, c1 = xk1, t0, t1, s0, s1;
  jx_subkey(c0, c1, 2u, 0u, t0, t1);
  jx_subkey(c0, c1, 2u, 1u, s0, s1);
  const float x1 = normal_from_bits(jx_bits(s0, s1, 1u, 0u));
  c0 = t0; c1 = t1;
  jx_subkey(c0, c1, 2u, 0u, t0, t1);
  jx_subkey(c0, c1, 2u, 1u, s0, s1);
  const float x2 = normal_from_bits(jx_bits(s0, s1, 1u, 0u));
  const float U1 = u01_from_bits(jx_bits(uk0, uk1, 1u, 0u));
  float* R = RND + (size_t)i * 4;
  R[0] = z; R[1] = x1; R[2] = x2; R[3] = U1;
}

// ---------------- kernel 1: tscale + feature build ----------------
__global__ void __launch_bounds__(256) prep_kernel(
    const float* __restrict__ X, const float* __restrict__ emb,
    float* __restrict__ inp, float* __restrict__ ct,
    float* __restrict__ tscale, float* __restrict__ ltscale)
{
  const int b = blockIdx.x, t = threadIdx.x;
  __shared__ float red[256];
  __shared__ float ts_sh;
  const float* Xb = X + (size_t)b * LFULL * NCH;
  float p = fabsf(Xb[(28 + t) * NCH]);
  if (t < 80) p += fabsf(Xb[(28 + 256 + t) * NCH]);
  red[t] = p;
  for (int st = 128; st > 0; st >>= 1) { __syncthreads(); if (t < st) red[t] += red[t + st]; }
  __syncthreads();
  if (t == 0) {
    float ts = red[0] / 336.0f;
    ts = fmaxf(ts, 1e-10f);
    tscale[b] = ts; ltscale[b] = logf(ts); ts_sh = ts;
  }
  __syncthreads();
  const float ts = ts_sh;
  const float lts = logf(ts);
  const float ev = emb[0];
  for (int idx = t; idx < TM1 * NIN; idx += 256) {
    const int tt = idx / NIN, f = idx - tt * NIN;
    float val;
    if (f == 0)       val = (tt < CTX) ? Xb[(28 + tt) * NCH] / ts : 0.0f;
    else if (f <= 10) val = (tt < CTX) ? Xb[(28 + tt - c_LAGS[f - 1]) * NCH] / ts : 0.0f;
    else if (f == 11) val = ev;
    else if (f == 12) val = Xb[(28 + tt) * NCH + 2];
    else if (f == 13) val = lts;
    else              val = Xb[(28 + tt) * NCH + 1];
    inp[(size_t)(b * TM1 + tt) * NIN + f] = val;
    if (f == 0 && tt < CTX) ct[b * CTX + tt] = val;
  }
}

// ---------------- kernel 2: context LSTM (fast cell transcendentals) ---------
__global__ void __launch_bounds__(256) ctx_lstm_kernel(
    const float* __restrict__ inp,
    const float* __restrict__ WTx, const float* __restrict__ WT00,
    const float* __restrict__ WT10, const float* __restrict__ WT11,
    const float* __restrict__ bih0, const float* __restrict__ bhh0,
    const float* __restrict__ bih1, const float* __restrict__ bhh1,
    const float* __restrict__ wdf, const float* __restrict__ bdfp,
    const float* __restrict__ wloc, const float* __restrict__ blocp,
    const float* __restrict__ wsc, const float* __restrict__ bscp,
    float* __restrict__ dfo, float* __restrict__ loco, float* __restrict__ sco,
    float* __restrict__ h0f, float* __restrict__ c0f,
    float* __restrict__ h1f, float* __restrict__ c1f)
{
  const int b = blockIdx.x, t = threadIdx.x;
  const int lane = t & 63, w = t >> 6;
  const int gbase = lane << 2;
  __shared__ __align__(16) float gA[4][256];
  __shared__ __align__(16) float gB[4][256];

  const float bs0 = bih0[lane]       + bhh0[lane];
  const float bs1 = bih0[64 + lane]  + bhh0[64 + lane];
  const float bs2 = bih0[128 + lane] + bhh0[128 + lane];
  const float bs3 = bih0[192 + lane] + bhh0[192 + lane];
  const float bs4 = bih1[lane]       + bhh1[lane];
  const float bs5 = bih1[64 + lane]  + bhh1[64 + lane];
  const float bs6 = bih1[128 + lane] + bhh1[128 + lane];
  const float bs7 = bih1[192 + lane] + bhh1[192 + lane];
  const float wdfv = wdf[lane], wlocv = wloc[lane], wscv = wsc[lane];
  const float bdf = bdfp[0], bloc = blocp[0], bsc = bscp[0];

  float h0r = 0.f, h1r = 0.f, c0r = 0.f, c1r = 0.f;
  const float* inb = inp + (size_t)b * TM1 * NIN;
  const int kx = w * 4;    // x-part k-quarter
  const int kh = w * 16;   // h-part k-quarter

  for (int tt = 0; tt < CTX; tt++) {
    float xr = 0.f;
    if (lane < 15) xr = inb[tt * NIN + lane];

    v2f aA = bc2(0.0f), aB = bc2(0.0f);
#pragma unroll
    for (int kk = 0; kk < 4; kk++) {
      const int k = kx + kk;
      const float4 wv = *(const float4*)&WTx[(k << 8) + gbase];
      v2f wlo, whi; wlo[0] = wv.x; wlo[1] = wv.y; whi[0] = wv.z; whi[1] = wv.w;
      const v2f hk = bc2(rl_f(xr, k));
      aA += wlo * hk; aB += whi * hk;
    }
#pragma unroll
    for (int kk = 0; kk < 16; kk++) {
      const int k = kh + kk;
      const float4 wv = *(const float4*)&WT00[(k << 8) + gbase];
      v2f wlo, whi; wlo[0] = wv.x; wlo[1] = wv.y; whi[0] = wv.z; whi[1] = wv.w;
      const v2f hk = bc2(rl_f(h0r, k));
      aA += wlo * hk; aB += whi * hk;
    }
    {
      float4 gv; gv.x = aA[0]; gv.y = aA[1]; gv.z = aB[0]; gv.w = aB[1];
      *(float4*)&gA[w][gbase] = gv;
    }
    __syncthreads();

    {
      float gi = ((gA[0][lane]       + gA[1][lane])       + gA[2][lane])       + gA[3][lane];
      float gf = ((gA[0][64 + lane]  + gA[1][64 + lane])  + gA[2][64 + lane])  + gA[3][64 + lane];
      float gg = ((gA[0][128 + lane] + gA[1][128 + lane]) + gA[2][128 + lane]) + gA[3][128 + lane];
      float go = ((gA[0][192 + lane] + gA[1][192 + lane]) + gA[2][192 + lane]) + gA[3][192 + lane];
      gi += bs0; gf += bs1; gg += bs2; go += bs3;
      c0r = sigm(gf) * c0r + sigm(gi) * tanh_fast(gg);
      h0r = sigm(go) * tanh_fast(c0r);
    }

    aA = bc2(0.0f); aB = bc2(0.0f);
#pragma unroll
    for (int kk = 0; kk < 16; kk++) {
      const int k = kh + kk;
      const float4 wv = *(const float4*)&WT10[(k << 8) + gbase];
      v2f wlo, whi; wlo[0] = wv.x; wlo[1] = wv.y; whi[0] = wv.z; whi[1] = wv.w;
      const v2f hk = bc2(rl_f(h0r, k));
      aA += wlo * hk; aB += whi * hk;
    }
#pragma unroll
    for (int kk = 0; kk < 16; kk++) {
      const int k = kh + kk;
      const float4 wv = *(const float4*)&WT11[(k << 8) + gbase];
      v2f wlo, whi; wlo[0] = wv.x; wlo[1] = wv.y; whi[0] = wv.z; whi[1] = wv.w;
      const v2f hk = bc2(rl_f(h1r, k));
      aA += wlo * hk; aB += whi * hk;
    }
    {
      float4 gv; gv.x = aA[0]; gv.y = aA[1]; gv.z = aB[0]; gv.w = aB[1];
      *(float4*)&gB[w][gbase] = gv;
    }
    __syncthreads();

    {
      float gi = ((gB[0][lane]       + gB[1][lane])       + gB[2][lane])       + gB[3][lane];
      float gf = ((gB[0][64 + lane]  + gB[1][64 + lane])  + gB[2][64 + lane])  + gB[3][64 + lane];
      float gg = ((gB[0][128 + lane] + gB[1][128 + lane]) + gB[2][128 + lane]) + gB[3][128 + lane];
      float go = ((gB[0][192 + lane] + gB[1][192 + lane]) + gB[2][192 + lane]) + gB[3][192 + lane];
      gi += bs4; gf += bs5; gg += bs6; go += bs7;
      c1r = sigm(gf) * c1r + sigm(gi) * tanh_fast(gg);
      h1r = sigm(go) * tanh_fast(c1r);
      if (w == 0) {
        float pd = h1r * wdfv, pl = h1r * wlocv, ps = h1r * wscv;
#pragma unroll
        for (int off = 32; off > 0; off >>= 1) {
          pd += __shfl_down(pd, off, 64);
          pl += __shfl_down(pl, off, 64);
          ps += __shfl_down(ps, off, 64);
        }
        if (lane == 0) {
          dfo[b * CTX + tt]  = 2.0f + softplusf(pd + bdf);
          loco[b * CTX + tt] = pl + bloc;
          sco[b * CTX + tt]  = softplusf(ps + bsc);
        }
      }
    }
  }
  if (w == 0) {
    h0f[b * 64 + lane] = h0r; c0f[b * 64 + lane] = c0r;
    h1f[b * 64 + lane] = h1r; c1f[b * 64 + lane] = c1r;
  }
}

// ---------------- kernel 3: context sampling (y_ctx) ----------------
__global__ void __launch_bounds__(256) ctx_sample_kernel(
    const float* __restrict__ df, const float* __restrict__ loc, const float* __restrict__ sc,
    const float* __restrict__ tscale, float* __restrict__ yhat,
    u32 kz0, u32 kz1, u32 kg0, u32 kg1)
{
  const int i = blockIdx.x * 256 + threadIdx.x;
  const int r = i / CTX, t = i - r * CTX;
  const int b = r / NSAMP;
  const float dfv = df[b * CTX + t], lv = loc[b * CTX + t], sv = sc[b * CTX + t];
  const float z = normal_from_bits(jx_bits(kz0, kz1, NCTXS, (u32)i));
  u32 gk0, gk1;
  jx_subkey(kg0, kg1, NCTXS, (u32)i, gk0, gk1);
  const float g = jax_gamma_one(gk0, gk1, dfv * 0.5f);
  const float y = (lv + sv * (z * sqrtf(dfv / (2.0f * g)))) * tscale[b];
  yhat[(size_t)r * TM1 + t] = y;
}

// ---------------- kernel 5: persistent decode (MFMA, low-VALU) ---------------
// R8: R7 fixed the spill (VGPR 104, FETCH 13 MB); now honestly VALU-bound
// (VALUBusy 65%, ~4400 inst/wave-step).  Cuts: (1) HW-native sigm/tanh in the
// cells (~1500 inst/wave-step); (2) head projection via 2 MFMAs on the head
// B-fragment (deletes 48 shfl_xor x3 + 48 fma + 12 regs); (3) loop-invariant
// hoisting: xh[11]=emb, xh[13]=log(ts) written once; 1/ts precomputed.
__global__ void __attribute__((amdgpu_flat_work_group_size(512, 512),
                               amdgpu_waves_per_eu(2, 2)))
dec_persist_kernel(
    const float* __restrict__ inp, const float* __restrict__ tscale,
    const f16* __restrict__ WH, const float* __restrict__ emb,
    const float* __restrict__ bih1, const float* __restrict__ bhh1,
    const float* __restrict__ bdfp, const float* __restrict__ blocp,
    const float* __restrict__ bscp,
    const float* __restrict__ h0f, const float* __restrict__ c0f,
    const float* __restrict__ h1f, const float* __restrict__ c1f,
    const float* __restrict__ ct, const float* __restrict__ RND,
    float* __restrict__ yhat, u32 kl0, u32 kl1)
{
  const int t    = threadIdx.x;
  const int lane = t & 63;
  const int w    = t >> 6;        // wave 0..7
  const int r0   = w * RPW;       // wave's first local row
  const int c16  = lane & 15;     // gate col within tile / A row select
  const int kg   = lane >> 4;     // k-group / D row-group

  __shared__ __align__(16) f16   wgt[WH_TOT];        // 106 KB B-fragment weights
  __shared__ __align__(16) f16   h0h[DROWS * HSTR];  // 18 KB
  __shared__ __align__(16) f16   h1h[DROWS * HSTR];  // 18 KB
  __shared__ __align__(16) f16   xh[DROWS][16];      // 4 KB (x features; [15]=1.0)
  __shared__ __align__(16) f16   xzero[32];          // shared K-pad zeros
  __shared__ __align__(16) f16   hist[DROWS][32];    // 8 KB lag ring
  __shared__ __align__(16) f16   fst[3][NSTEP][2];   // X ch2 / ch1 stash
  __shared__ __align__(16) float b1L[4][4][16];      // layer-1 bias table, 1 KB
  __shared__ float tsr[DROWS], itsr[DROWS];
  __shared__ float dfL[DROWS], locL[DROWS], scL[DROWS];
  __shared__ unsigned char rsel[DROWS];

  const int base = blockIdx.x * DROWS;
  const int bblo = base / NSAMP;

  // ---- stage all weights once: 106 x (64 lanes x 16B) chunks ----
  for (int i = w; i < WH_TOT / 512; i += 8) {
    const int off = i * 512;   // halves
    __builtin_amdgcn_global_load_lds(
        (const __attribute__((address_space(1))) void*)(WH + off + lane * 8),
        (__attribute__((address_space(3))) void*)(wgt + off), 16, 0, 0);
  }

  const float bdf = bdfp[0], bloc = blocp[0], bsc = bscp[0];
  const float embv = emb[0];

  float c0reg[4][4], c1reg[4][4];
#pragma unroll
  for (int rr = 0; rr < 4; rr++) {
    const int row = r0 + kg * 4 + rr;
    const int bb = (base + row) / NSAMP;
#pragma unroll
    for (int tq = 0; tq < 4; tq++) {
      c0reg[rr][tq] = c0f[bb * 64 + tq * 16 + c16];
      c1reg[rr][tq] = c1f[bb * 64 + tq * 16 + c16];
    }
  }

  // ---- h state into LDS (stride HSTR) ----
  for (int idx = t; idx < DROWS * 64; idx += 512) {
    const int row = idx >> 6, hid = idx & 63;
    const int bb = (base + row) / NSAMP;
    h0h[row * HSTR + hid] = (f16)h0f[bb * 64 + hid];
    h1h[row * HSTR + hid] = (f16)h1f[bb * 64 + hid];
  }

  for (int idx = t; idx < DROWS * 28; idx += 512) {
    const int i = idx / 28, k = idx - i * 28;
    const int bb = (base + i) / NSAMP;
    hist[i][31 - k] = (f16)ct[bb * CTX + 335 - k];
  }
  // feature stash (X ch2 @f=12, X ch1 @f=14); block spans <=3 batch indices
  for (int idx = t; idx < 3 * NSTEP * 2; idx += 512) {
    const int sel = idx / (NSTEP * 2), rem = idx - sel * (NSTEP * 2);
    const int s = rem >> 1, f = rem & 1;
    const int bb = min(bblo + sel, NB - 1);
    fst[sel][s][f] = (f16)inp[((size_t)bb * TM1 + CTX + s) * NIN + (f ? 14 : 12)];
  }
  if (t >= 192 && t < 448) {
    const int g = t - 192;                 // 0..255
    const int gq = g >> 6, rem = g & 63;
    b1L[gq][rem >> 4][rem & 15] = bih1[g] + bhh1[g];
  } else if (t >= 448 && t < 480) {
    xzero[t - 448] = (f16)0.0f;            // shared K-pad zero row
  }
  if (t < DROWS) {
    const int rg = base + t;
    const float ts = tscale[rg / NSAMP];
    tsr[t] = ts;
    itsr[t] = 1.0f / ts;
    xh[t][11] = (f16)embv;                 // loop-invariant features
    xh[t][13] = (f16)logf(ts);
    xh[t][15] = (f16)1.0f;                 // bias lane (W[k=15]=b0)
    rsel[t] = (unsigned char)((rg / NSAMP) - bblo);
  }
  float prevreg = 0.f;
  if (lane < RPW) prevreg = yhat[(size_t)(base + r0 + lane) * TM1 + 335];
  __syncthreads();   // covers weight staging (vmcnt drain) + all init writes

  const int arow = r0 + c16;         // A-fragment row for this lane
  // x A-frag source: kg 0,1 read the 16 real slots; kg 2,3 read shared zeros
  const f16* axp = (kg < 2) ? &xh[arow][kg * 8] : &xzero[(kg - 2) * 8];

#define BFR(off) (*(const half8*)&wgt[(off) + lane * 8])

  for (int s = 0; s < NSTEP; s++) {
    // ---- parallel x-build (slots 0..10,12,14; 11/13/15 invariant) ----
    if (lane < RPW) {
      const int row = r0 + lane;
      const f16 nh = (f16)(prevreg * itsr[row]);
      xh[row][0] = nh;
      hist[row][s & 31] = nh;
    }
    {
      const int rq = lane >> 2, q = lane & 3;
      const int row = r0 + rq;
#pragma unroll
      for (int p = 0; p < 4; p++) {
        const int sl = 1 + q + p * 4;          // 1..16
        if (sl <= 10) {
          xh[row][sl] = hist[row][(s - c_LAGS[sl - 1]) & 31];
        } else if (sl == 12) {
          xh[row][sl] = fst[rsel[row]][s][0];
        } else if (sl == 14) {
          xh[row][sl] = fst[rsel[row]][s][1];
        }
      }
    }

    // ---- layer 0: A-frags, then per-gate-column (tq) MFMA + cell ----
    const half8 ax  = *(const half8*)axp;
    const half8 a00 = *(const half8*)&h0h[arow * HSTR + kg * 8];
    const half8 a01 = *(const half8*)&h0h[arow * HSTR + 32 + kg * 8];
#pragma unroll
    for (int tq = 0; tq < 4; tq++) {
      floatx4 ai = {0.f, 0.f, 0.f, 0.f};
      floatx4 af = {0.f, 0.f, 0.f, 0.f};
      floatx4 ag = {0.f, 0.f, 0.f, 0.f};
      floatx4 ao = {0.f, 0.f, 0.f, 0.f};
      ai = __builtin_amdgcn_mfma_f32_16x16x32_f16(ax, BFR(WH_X + (tq)      * 256), ai, 0, 0, 0);
      af = __builtin_amdgcn_mfma_f32_16x16x32_f16(ax, BFR(WH_X + (4 + tq)  * 256), af, 0, 0, 0);
      ag = __builtin_amdgcn_mfma_f32_16x16x32_f16(ax, BFR(WH_X + (8 + tq)  * 256), ag, 0, 0, 0);
      ao = __builtin_amdgcn_mfma_f32_16x16x32_f16(ax, BFR(WH_X + (12 + tq) * 256), ao, 0, 0, 0);
      ai = __builtin_amdgcn_mfma_f32_16x16x32_f16(a00, BFR(WH_00 + ((tq) * 2 + 0)      * 512), ai, 0, 0, 0);
      ai = __builtin_amdgcn_mfma_f32_16x16x32_f16(a01, BFR(WH_00 + ((tq) * 2 + 1)      * 512), ai, 0, 0, 0);
      af = __builtin_amdgcn_mfma_f32_16x16x32_f16(a00, BFR(WH_00 + ((4 + tq) * 2 + 0)  * 512), af, 0, 0, 0);
      af = __builtin_amdgcn_mfma_f32_16x16x32_f16(a01, BFR(WH_00 + ((4 + tq) * 2 + 1)  * 512), af, 0, 0, 0);
      ag = __builtin_amdgcn_mfma_f32_16x16x32_f16(a00, BFR(WH_00 + ((8 + tq) * 2 + 0)  * 512), ag, 0, 0, 0);
      ag = __builtin_amdgcn_mfma_f32_16x16x32_f16(a01, BFR(WH_00 + ((8 + tq) * 2 + 1)  * 512), ag, 0, 0, 0);
      ao = __builtin_amdgcn_mfma_f32_16x16x32_f16(a00, BFR(WH_00 + ((12 + tq) * 2 + 0) * 512), ao, 0, 0, 0);
      ao = __builtin_amdgcn_mfma_f32_16x16x32_f16(a01, BFR(WH_00 + ((12 + tq) * 2 + 1) * 512), ao, 0, 0, 0);
#pragma unroll
      for (int rr = 0; rr < 4; rr++) {
        const float gi = ai[rr], gf = af[rr], gg = ag[rr], go = ao[rr];
        float cc = c0reg[rr][tq];
        cc = sigm(gf) * cc + sigm(gi) * tanh_fast(gg);
        c0reg[rr][tq] = cc;
        h0h[(r0 + kg * 4 + rr) * HSTR + tq * 16 + c16] = (f16)(sigm(go) * tanh_fast(cc));
      }
      __builtin_amdgcn_sched_barrier(0);   // cap cross-tq hoisting (reg pressure)
    }

    // ---- layer 1: A-frags (h0_new complete), per-tq MFMA + cell ----
    const half8 a10a = *(const half8*)&h0h[arow * HSTR + kg * 8];
    const half8 a10b = *(const half8*)&h0h[arow * HSTR + 32 + kg * 8];
    const half8 a11a = *(const half8*)&h1h[arow * HSTR + kg * 8];
    const half8 a11b = *(const half8*)&h1h[arow * HSTR + 32 + kg * 8];
#pragma unroll
    for (int tq = 0; tq < 4; tq++) {
      const float bi = b1L[0][tq][c16];
      const float bf = b1L[1][tq][c16];
      const float bg = b1L[2][tq][c16];
      const float bo = b1L[3][tq][c16];
      floatx4 ai = {bi, bi, bi, bi};
      floatx4 af = {bf, bf, bf, bf};
      floatx4 ag = {bg, bg, bg, bg};
      floatx4 ao = {bo, bo, bo, bo};
      ai = __builtin_amdgcn_mfma_f32_16x16x32_f16(a10a, BFR(WH_10 + ((tq) * 2 + 0)      * 512), ai, 0, 0, 0);
      ai = __builtin_amdgcn_mfma_f32_16x16x32_f16(a10b, BFR(WH_10 + ((tq) * 2 + 1)      * 512), ai, 0, 0, 0);
      ai = __builtin_amdgcn_mfma_f32_16x16x32_f16(a11a, BFR(WH_11 + ((tq) * 2 + 0)      * 512), ai, 0, 0, 0);
      ai = __builtin_amdgcn_mfma_f32_16x16x32_f16(a11b, BFR(WH_11 + ((tq) * 2 + 1)      * 512), ai, 0, 0, 0);
      af = __builtin_amdgcn_mfma_f32_16x16x32_f16(a10a, BFR(WH_10 + ((4 + tq) * 2 + 0)  * 512), af, 0, 0, 0);
      af = __builtin_amdgcn_mfma_f32_16x16x32_f16(a10b, BFR(WH_10 + ((4 + tq) * 2 + 1)  * 512), af, 0, 0, 0);
      af = __builtin_amdgcn_mfma_f32_16x16x32_f16(a11a, BFR(WH_11 + ((4 + tq) * 2 + 0)  * 512), af, 0, 0, 0);
      af = __builtin_amdgcn_mfma_f32_16x16x32_f16(a11b, BFR(WH_11 + ((4 + tq) * 2 + 1)  * 512), af, 0, 0, 0);
      ag = __builtin_amdgcn_mfma_f32_16x16x32_f16(a10a, BFR(WH_10 + ((8 + tq) * 2 + 0)  * 512), ag, 0, 0, 0);
      ag = __builtin_amdgcn_mfma_f32_16x16x32_f16(a10b, BFR(WH_10 + ((8 + tq) * 2 + 1)  * 512), ag, 0, 0, 0);
      ag = __builtin_amdgcn_mfma_f32_16x16x32_f16(a11a, BFR(WH_11 + ((8 + tq) * 2 + 0)  * 512), ag, 0, 0, 0);
      ag = __builtin_amdgcn_mfma_f32_16x16x32_f16(a11b, BFR(WH_11 + ((8 + tq) * 2 + 1)  * 512), ag, 0, 0, 0);
      ao = __builtin_amdgcn_mfma_f32_16x16x32_f16(a10a, BFR(WH_10 + ((12 + tq) * 2 + 0) * 512), ao, 0, 0, 0);
      ao = __builtin_amdgcn_mfma_f32_16x16x32_f16(a10b, BFR(WH_10 + ((12 + tq) * 2 + 1) * 512), ao, 0, 0, 0);
      ao = __builtin_amdgcn_mfma_f32_16x16x32_f16(a11a, BFR(WH_11 + ((12 + tq) * 2 + 0) * 512), ao, 0, 0, 0);
      ao = __builtin_amdgcn_mfma_f32_16x16x32_f16(a11b, BFR(WH_11 + ((12 + tq) * 2 + 1) * 512), ao, 0, 0, 0);
#pragma unroll
      for (int rr = 0; rr < 4; rr++) {
        const float gi = ai[rr], gf = af[rr], gg = ag[rr], go = ao[rr];
        float cc = c1reg[rr][tq];
        cc = sigm(gf) * cc + sigm(gi) * tanh_fast(gg);
        c1reg[rr][tq] = cc;
        h1h[(r0 + kg * 4 + rr) * HSTR + tq * 16 + c16] = (f16)(sigm(go) * tanh_fast(cc));
      }
      __builtin_amdgcn_sched_barrier(0);   // cap cross-tq hoisting (reg pressure)
    }

    // ---- head via 2 MFMAs on h1_new (cols 0/1/2 = df/loc/sc) ----
    {
      const half8 an0 = *(const half8*)&h1h[arow * HSTR + kg * 8];
      const half8 an1 = *(const half8*)&h1h[arow * HSTR + 32 + kg * 8];
      floatx4 hd = {0.f, 0.f, 0.f, 0.f};
      hd = __builtin_amdgcn_mfma_f32_16x16x32_f16(an0, BFR(WH_HD + 0 * 512), hd, 0, 0, 0);
      hd = __builtin_amdgcn_mfma_f32_16x16x32_f16(an1, BFR(WH_HD + 1 * 512), hd, 0, 0, 0);
      if (c16 == 0) {
#pragma unroll
        for (int rr = 0; rr < 4; rr++)
          dfL[r0 + kg * 4 + rr] = 2.0f + softplusf(hd[rr] + bdf);
      } else if (c16 == 1) {
#pragma unroll
        for (int rr = 0; rr < 4; rr++)
          locL[r0 + kg * 4 + rr] = hd[rr] + bloc;
      } else if (c16 == 2) {
#pragma unroll
        for (int rr = 0; rr < 4; rr++)
          scL[r0 + kg * 4 + rr] = softplusf(hd[rr] + bsc);
      }
    }

    // ---- sample (one lane per row, 16 rows in parallel) ----
    if (lane < RPW) {
      const int row = r0 + lane, rg = base + row;
      const float4 R = *(const float4*)(RND + ((size_t)s * RTOT + rg) * 4);
      const float dfv = dfL[row], lv = locL[row], scv = scL[row];
      const float z = R.x;
      const float alpha = dfv * 0.5f;
      float gam;
      {
#pragma clang fp contract(off)
        const float d = alpha - 0.33333334f;
        const float c = 0.33333334f / sqrtf(d);
        float x = R.y;
        float v = 1.0f + x * c;
        bool ok = true;
        if (v <= 0.0f) { x = R.z; v = 1.0f + x * c; ok = (v > 0.0f); }
        const float X = x * x;
        const float V = (v * v) * v;
        const float U = R.w;
        bool accept = false;
        if (ok) {
          if (!(U >= 1.0f - 0.0331f * (X * X))) accept = true;
          else if (!(logf(U) >= 0.5f * X + d * ((1.0f - V) + logf(V)))) accept = true;
        }
        if (accept) {
          gam = d * V;
        } else {
          u32 ks0, ks1, skg0, skg1, gk0, gk1;
          tf2x32(kl0, kl1, 0u, (u32)s, ks0, ks1);
          tf2x32(ks0, ks1, 0u, 1u, skg0, skg1);
          jx_subkey(skg0, skg1, RTOT, (u32)rg, gk0, gk1);
          gam = jax_gamma_one(gk0, gk1, alpha);
        }
      }
      const float y = (lv + scv * (z * sqrtf(dfv / (2.0f * gam)))) * tsr[row];
      yhat[(size_t)rg * TM1 + CTX + s] = y;
      prevreg = y;
    }
  }
#undef BFR
}

// ---------------- kernel 6: median over 100 samples per (b,t) ----------------
__global__ void __launch_bounds__(256) median_kernel(
    const float* __restrict__ yhat, float* __restrict__ out)
{
  __shared__ float vals[4][100];
  const int wave = threadIdx.x >> 6, lane = threadIdx.x & 63;
  const int cell = blockIdx.x * 4 + wave;
  const int b = cell / TM1, t = cell - b * TM1;
  const float* basep = yhat + (size_t)b * NSAMP * TM1 + t;
  const float v1 = basep[(size_t)lane * TM1];
  vals[wave][lane] = v1;
  float v2 = 0.f;
  if (lane < 36) { v2 = basep[(size_t)(64 + lane) * TM1]; vals[wave][64 + lane] = v2; }
  __syncthreads();
  int cl1 = 0, ce1 = 0, cl2 = 0, ce2 = 0;
  for (int jj = 0; jj < 100; jj++) {
    const float w = vals[wave][jj];
    cl1 += (w < v1); ce1 += (w == v1);
    cl2 += (w < v2); ce2 += (w == v2);
  }
  if (cl1 <= 49 && 49 < cl1 + ce1) out[cell] = v1;
  if (lane < 36 && cl2 <= 49 && 49 < cl2 + ce2) out[cell] = v2;
}

// ---------------- launch ----------------
extern "C" void kernel_launch(void* const* d_in, const int* in_sizes, int n_in,
                              void* d_out, int out_size, void* d_ws, size_t ws_size,
                              hipStream_t stream) {
  (void)in_sizes; (void)n_in; (void)out_size; (void)ws_size;
  const float* X     = (const float*)d_in[0];
  const float* Wih0  = (const float*)d_in[2];
  const float* Whh0  = (const float*)d_in[3];
  const float* bih0  = (const float*)d_in[4];
  const float* bhh0  = (const float*)d_in[5];
  const float* Wih1  = (const float*)d_in[6];
  const float* Whh1  = (const float*)d_in[7];
  const float* bih1  = (const float*)d_in[8];
  const float* bhh1  = (const float*)d_in[9];
  const float* wdf   = (const float*)d_in[10];
  const float* bdf   = (const float*)d_in[11];
  const float* wloc  = (const float*)d_in[12];
  const float* bloc  = (const float*)d_in[13];
  const float* wsc   = (const float*)d_in[14];
  const float* bsc   = (const float*)d_in[15];
  const float* emb   = (const float*)d_in[16];

  float* wsf = (float*)d_ws;
  float* inp  = wsf + OFF_INP;
  float* ct   = wsf + OFF_CT;
  float* ts   = wsf + OFF_TS;
  float* lts  = wsf + OFF_LTS;
  float* dfp  = wsf + OFF_DF;
  float* locp = wsf + OFF_LOC;
  float* scp  = wsf + OFF_SC;
  float* h0f  = wsf + OFF_H0F;
  float* c0f  = wsf + OFF_C0F;
  float* h1f  = wsf + OFF_H1F;
  float* c1f  = wsf + OFF_C1F;
  float* yhat = wsf + OFF_YH;
  float* wtx  = wsf + OFF_WTX;
  float* wt00 = wsf + OFF_WT00;
  float* wt10 = wsf + OFF_WT10;
  float* wt11 = wsf + OFF_WT11;
  f16*   wh   = (f16*)(wsf + OFF_WH);
  float* rnd  = wsf + OFF_RND;

  const u32 key0 = 0u, key1 = 42u;
  u32 kc0, kc1, kl0, kl1;
  jx_subkey(key0, key1, 2u, 0u, kc0, kc1);
  jx_subkey(key0, key1, 2u, 1u, kl0, kl1);
  u32 kz0, kz1, kg0, kg1;
  jx_subkey(kc0, kc1, 2u, 0u, kz0, kz1);
  jx_subkey(kc0, kc1, 2u, 1u, kg0, kg1);

  wtrans_kernel<<<208, 256, 0, stream>>>(Wih0, Whh0, Wih1, Whh1, wtx, wt00, wt10, wt11);
  wh_kernel<<<212, 256, 0, stream>>>(Wih0, Whh0, Wih1, Whh1, bih0, bhh0,
                                     wdf, wloc, wsc, wh);
  rnd_dec_kernel<<<(NSTEP * RTOT) / 256, 256, 0, stream>>>(rnd, kl0, kl1);
  prep_kernel<<<NB, 256, 0, stream>>>(X, emb, inp, ct, ts, lts);
  ctx_lstm_kernel<<<NB, 256, 0, stream>>>(inp, wtx, wt00, wt10, wt11,
                                          bih0, bhh0, bih1, bhh1,
                                          wdf, bdf, wloc, bloc, wsc, bsc,
                                          dfp, locp, scp, h0f, c0f, h1f, c1f);
  ctx_sample_kernel<<<NCTXS / 256, 256, 0, stream>>>(dfp, locp, scp, ts, yhat, kz0, kz1, kg0, kg1);
  dec_persist_kernel<<<DBLOCKS, 512, 0, stream>>>(inp, ts, wh, emb,
                                                  bih1, bhh1,
                                                  bdf, bloc, bsc,
                                                  h0f, c0f, h1f, c1f, ct, rnd, yhat, kl0, kl1);
  median_kernel<<<(NB * TM1) / 4, 256, 0, stream>>>(yhat, (float*)d_out);
}